// Round 1
// baseline (4634.775 us; speedup 1.0000x reference)
//
#include <hip/hip_runtime.h>
#include <hip/hip_bf16.h>

#define B_ 4
#define S_ 2048
#define E_ 100
#define F_ 64
#define C_ 8922
#define V_ 52000

// ---------------------------------------------------------------------------
// Kernel 1: embedding lookup + 4 dilation-free 'same' convs + tanh
// grid: B * (S/32) blocks, 256 threads (f = t&63, s-group = t>>6, 8 s each)
// h layout: [branch][b][s][f]  (f contiguous)
// ---------------------------------------------------------------------------
__global__ __launch_bounds__(256) void conv_tanh_kernel(
    const int* __restrict__ x, const float* __restrict__ embed,
    const float* __restrict__ w3, const float* __restrict__ b3,
    const float* __restrict__ w5, const float* __restrict__ b5,
    const float* __restrict__ w7, const float* __restrict__ b7,
    const float* __restrict__ w9, const float* __restrict__ b9,
    float* __restrict__ h)
{
    // xe tile transposed: [E][40] rows s0-4 .. s0+35 (halo 4 each side for k=9)
    __shared__ float xe[E_ * 40];

    const int blk = blockIdx.x;
    const int b   = blk / (S_ / 32);
    const int st  = blk % (S_ / 32);
    const int s0  = st * 32;
    const int t   = threadIdx.x;

    for (int idx = t; idx < E_ * 40; idx += 256) {
        const int e = idx / 40;
        const int r = idx - e * 40;
        const int s = s0 - 4 + r;
        float v = 0.f;
        if (s >= 0 && s < S_) {
            const int tok = x[b * S_ + s];
            v = embed[tok * E_ + e];
        }
        xe[e * 40 + r] = v;
    }
    __syncthreads();

    const int f      = t & 63;
    const int sg     = t >> 6;   // 0..3
    const int slbase = sg * 8;   // this thread covers s_local slbase..slbase+7

    float acc3[8] = {0}, acc5[8] = {0}, acc7[8] = {0}, acc9[8] = {0};

    const float* __restrict__ w3f = w3 + f * E_ * 3;
    const float* __restrict__ w5f = w5 + f * E_ * 5;
    const float* __restrict__ w7f = w7 + f * E_ * 7;
    const float* __restrict__ w9f = w9 + f * E_ * 9;

    for (int e = 0; e < E_; ++e) {
        // 16-value input window for this thread's 8 outputs + k=9 halo
        float win[16];
        const float* base = &xe[e * 40 + slbase];
        *(float4*)&win[0]  = *(const float4*)&base[0];
        *(float4*)&win[4]  = *(const float4*)&base[4];
        *(float4*)&win[8]  = *(const float4*)&base[8];
        *(float4*)&win[12] = *(const float4*)&base[12];

        float W3[3], W5[5], W7[7], W9[9];
        #pragma unroll
        for (int d = 0; d < 3; ++d) W3[d] = w3f[e * 3 + d];
        #pragma unroll
        for (int d = 0; d < 5; ++d) W5[d] = w5f[e * 5 + d];
        #pragma unroll
        for (int d = 0; d < 7; ++d) W7[d] = w7f[e * 7 + d];
        #pragma unroll
        for (int d = 0; d < 9; ++d) W9[d] = w9f[e * 9 + d];

        #pragma unroll
        for (int i = 0; i < 8; ++i) {
            // window index for branch k at tap dk: i + dk + 4 - k/2
            #pragma unroll
            for (int d = 0; d < 3; ++d) acc3[i] = fmaf(win[i + d + 3], W3[d], acc3[i]);
            #pragma unroll
            for (int d = 0; d < 5; ++d) acc5[i] = fmaf(win[i + d + 2], W5[d], acc5[i]);
            #pragma unroll
            for (int d = 0; d < 7; ++d) acc7[i] = fmaf(win[i + d + 1], W7[d], acc7[i]);
            #pragma unroll
            for (int d = 0; d < 9; ++d) acc9[i] = fmaf(win[i + d + 0], W9[d], acc9[i]);
        }
    }

    const float bb3 = b3[f], bb5 = b5[f], bb7 = b7[f], bb9 = b9[f];
    #pragma unroll
    for (int i = 0; i < 8; ++i) {
        const int s = s0 + slbase + i;
        h[((0 * B_ + b) * S_ + s) * F_ + f] = tanhf(acc3[i] + bb3);
        h[((1 * B_ + b) * S_ + s) * F_ + f] = tanhf(acc5[i] + bb5);
        h[((2 * B_ + b) * S_ + s) * F_ + f] = tanhf(acc7[i] + bb7);
        h[((3 * B_ + b) * S_ + s) * F_ + f] = tanhf(acc9[i] + bb9);
    }
}

// ---------------------------------------------------------------------------
// Kernel 2: fused scores -> softmax(S) -> weighted sum (flash-style, fp32)
// grid: (ceil(C/128), B, 4branches), 128 threads, one c per thread
// mten layout: [branch][b][c][f]
// ---------------------------------------------------------------------------
__global__ __launch_bounds__(128) void attn_kernel(
    const float* __restrict__ U3, const float* __restrict__ U5,
    const float* __restrict__ U7, const float* __restrict__ U9,
    const float* __restrict__ h, float* __restrict__ mten)
{
    __shared__ float hs[16 * F_];   // 4 KB tile of h rows

    const int ct = blockIdx.x;
    const int b  = blockIdx.y;
    const int br = blockIdx.z;
    const int c  = ct * 128 + threadIdx.x;
    const bool valid = (c < C_);

    const float* __restrict__ U =
        (br == 0) ? U3 : (br == 1) ? U5 : (br == 2) ? U7 : U9;
    const float* __restrict__ hb = h + (br * B_ + b) * (S_ * F_);

    float q[F_];
    if (valid) {
        const float4* qr = (const float4*)(U + c * F_);
        #pragma unroll
        for (int f4 = 0; f4 < 16; ++f4) *(float4*)&q[f4 * 4] = qr[f4];
    } else {
        #pragma unroll
        for (int f = 0; f < F_; ++f) q[f] = 0.f;
    }

    float m_run = -1e30f, l_run = 0.f;
    float acc[F_];
    #pragma unroll
    for (int f = 0; f < F_; ++f) acc[f] = 0.f;

    for (int s0 = 0; s0 < S_; s0 += 16) {
        __syncthreads();
        // cooperative stage: 16 rows x 64 f = 256 float4, 128 threads x 2
        const float4* src = (const float4*)(hb + s0 * F_);
        float4* dst = (float4*)hs;
        dst[threadIdx.x]       = src[threadIdx.x];
        dst[threadIdx.x + 128] = src[threadIdx.x + 128];
        __syncthreads();

        float sc[16];
        #pragma unroll
        for (int j = 0; j < 16; ++j) {
            float d0 = 0.f, d1 = 0.f, d2 = 0.f, d3 = 0.f;
            #pragma unroll
            for (int f4 = 0; f4 < 16; f4 += 4) {
                const float4 h0 = *(const float4*)&hs[j * F_ + (f4 + 0) * 4];
                const float4 h1 = *(const float4*)&hs[j * F_ + (f4 + 1) * 4];
                const float4 h2 = *(const float4*)&hs[j * F_ + (f4 + 2) * 4];
                const float4 h3 = *(const float4*)&hs[j * F_ + (f4 + 3) * 4];
                d0 = fmaf(q[(f4+0)*4+0], h0.x, d0); d0 = fmaf(q[(f4+0)*4+1], h0.y, d0);
                d0 = fmaf(q[(f4+0)*4+2], h0.z, d0); d0 = fmaf(q[(f4+0)*4+3], h0.w, d0);
                d1 = fmaf(q[(f4+1)*4+0], h1.x, d1); d1 = fmaf(q[(f4+1)*4+1], h1.y, d1);
                d1 = fmaf(q[(f4+1)*4+2], h1.z, d1); d1 = fmaf(q[(f4+1)*4+3], h1.w, d1);
                d2 = fmaf(q[(f4+2)*4+0], h2.x, d2); d2 = fmaf(q[(f4+2)*4+1], h2.y, d2);
                d2 = fmaf(q[(f4+2)*4+2], h2.z, d2); d2 = fmaf(q[(f4+2)*4+3], h2.w, d2);
                d3 = fmaf(q[(f4+3)*4+0], h3.x, d3); d3 = fmaf(q[(f4+3)*4+1], h3.y, d3);
                d3 = fmaf(q[(f4+3)*4+2], h3.z, d3); d3 = fmaf(q[(f4+3)*4+3], h3.w, d3);
            }
            sc[j] = (d0 + d1) + (d2 + d3);
        }

        float tmax = sc[0];
        #pragma unroll
        for (int j = 1; j < 16; ++j) tmax = fmaxf(tmax, sc[j]);

        if (tmax > m_run) {
            const float corr = __expf(m_run - tmax);
            l_run *= corr;
            #pragma unroll
            for (int f = 0; f < F_; ++f) acc[f] *= corr;
            m_run = tmax;
        }

        #pragma unroll
        for (int j = 0; j < 16; ++j) {
            const float p = __expf(sc[j] - m_run);
            l_run += p;
            #pragma unroll
            for (int f4 = 0; f4 < 16; ++f4) {
                const float4 hv = *(const float4*)&hs[j * F_ + f4 * 4];
                acc[f4*4+0] = fmaf(p, hv.x, acc[f4*4+0]);
                acc[f4*4+1] = fmaf(p, hv.y, acc[f4*4+1]);
                acc[f4*4+2] = fmaf(p, hv.z, acc[f4*4+2]);
                acc[f4*4+3] = fmaf(p, hv.w, acc[f4*4+3]);
            }
        }
    }

    if (valid) {
        const float inv = 1.f / l_run;
        float4* mo = (float4*)(mten + ((br * B_ + b) * C_ + c) * F_);
        #pragma unroll
        for (int f4 = 0; f4 < 16; ++f4) {
            float4 v;
            v.x = acc[f4*4+0] * inv; v.y = acc[f4*4+1] * inv;
            v.z = acc[f4*4+2] * inv; v.w = acc[f4*4+3] * inv;
            mo[f4] = v;
        }
    }
}

// ---------------------------------------------------------------------------
// Kernel 3: y_hat = sum(Wf * concat(m), axis=feat) + bf ; per-block BCE partials
// ---------------------------------------------------------------------------
__global__ __launch_bounds__(256) void final_kernel(
    const float* __restrict__ mten, const float* __restrict__ Wf,
    const float* __restrict__ bf, const float* __restrict__ y,
    float* __restrict__ out, float* __restrict__ partials)
{
    const int p = blockIdx.x * 256 + threadIdx.x;
    float bce = 0.f;
    if (p < B_ * C_) {
        const int b = p / C_;
        const int c = p - b * C_;
        float a0 = 0.f, a1 = 0.f, a2 = 0.f, a3 = 0.f;
        #pragma unroll
        for (int br = 0; br < 4; ++br) {
            const float4* mr = (const float4*)(mten + ((br * B_ + b) * C_ + c) * F_);
            const float4* wr = (const float4*)(Wf + c * (4 * F_) + br * F_);
            #pragma unroll
            for (int f4 = 0; f4 < 16; f4 += 4) {
                const float4 m0 = mr[f4+0], w0 = wr[f4+0];
                const float4 m1 = mr[f4+1], w1 = wr[f4+1];
                const float4 m2 = mr[f4+2], w2 = wr[f4+2];
                const float4 m3 = mr[f4+3], w3v = wr[f4+3];
                a0 = fmaf(m0.x,w0.x,a0); a0 = fmaf(m0.y,w0.y,a0); a0 = fmaf(m0.z,w0.z,a0); a0 = fmaf(m0.w,w0.w,a0);
                a1 = fmaf(m1.x,w1.x,a1); a1 = fmaf(m1.y,w1.y,a1); a1 = fmaf(m1.z,w1.z,a1); a1 = fmaf(m1.w,w1.w,a1);
                a2 = fmaf(m2.x,w2.x,a2); a2 = fmaf(m2.y,w2.y,a2); a2 = fmaf(m2.z,w2.z,a2); a2 = fmaf(m2.w,w2.w,a2);
                a3 = fmaf(m3.x,w3v.x,a3); a3 = fmaf(m3.y,w3v.y,a3); a3 = fmaf(m3.z,w3v.z,a3); a3 = fmaf(m3.w,w3v.w,a3);
            }
        }
        const float yh = (a0 + a1) + (a2 + a3) + bf[c];
        out[p] = yh;
        const float yy = y[p];
        bce = fmaxf(yh, 0.f) - yh * yy + log1pf(expf(-fabsf(yh)));
    }
    __shared__ float red[256];
    red[threadIdx.x] = bce;
    __syncthreads();
    #pragma unroll
    for (int stp = 128; stp > 0; stp >>= 1) {
        if (threadIdx.x < stp) red[threadIdx.x] += red[threadIdx.x + stp];
        __syncthreads();
    }
    if (threadIdx.x == 0) partials[blockIdx.x] = red[0];
}

__global__ __launch_bounds__(256) void loss_kernel(
    const float* __restrict__ partials, int n, float* __restrict__ out_loss)
{
    __shared__ float red[256];
    float v = (threadIdx.x < n) ? partials[threadIdx.x] : 0.f;
    red[threadIdx.x] = v;
    __syncthreads();
    #pragma unroll
    for (int stp = 128; stp > 0; stp >>= 1) {
        if (threadIdx.x < stp) red[threadIdx.x] += red[threadIdx.x + stp];
        __syncthreads();
    }
    if (threadIdx.x == 0) *out_loss = red[0] / (float)(B_ * C_);
}

// ---------------------------------------------------------------------------
extern "C" void kernel_launch(void* const* d_in, const int* in_sizes, int n_in,
                              void* d_out, int out_size, void* d_ws, size_t ws_size,
                              hipStream_t stream)
{
    const int*   x     = (const int*)  d_in[0];
    const float* y     = (const float*)d_in[1];
    const float* embed = (const float*)d_in[2];
    const float* w3    = (const float*)d_in[3];
    const float* b3    = (const float*)d_in[4];
    const float* w5    = (const float*)d_in[5];
    const float* b5    = (const float*)d_in[6];
    const float* w7    = (const float*)d_in[7];
    const float* b7    = (const float*)d_in[8];
    const float* w9    = (const float*)d_in[9];
    const float* b9    = (const float*)d_in[10];
    const float* U3    = (const float*)d_in[11];
    const float* U5    = (const float*)d_in[12];
    const float* U7    = (const float*)d_in[13];
    const float* U9    = (const float*)d_in[14];
    const float* Wf    = (const float*)d_in[15];
    const float* bfv   = (const float*)d_in[16];

    float* ws       = (float*)d_ws;
    float* h        = ws;                               // 4*B*S*F   = 2,097,152 f
    float* mten     = ws + 4 * B_ * S_ * F_;            // 4*B*C*F   = 9,136,128 f
    float* partials = mten + 4 * B_ * C_ * F_;          // 140 f
    float* out      = (float*)d_out;

    conv_tanh_kernel<<<B_ * (S_ / 32), 256, 0, stream>>>(
        x, embed, w3, b3, w5, b5, w7, b7, w9, b9, h);

    dim3 ag((C_ + 127) / 128, B_, 4);
    attn_kernel<<<ag, 128, 0, stream>>>(U3, U5, U7, U9, h, mten);

    const int nblk = (B_ * C_ + 255) / 256;   // 140
    final_kernel<<<nblk, 256, 0, stream>>>(mten, Wf, bfv, y, out, partials);
    loss_kernel<<<1, 256, 0, stream>>>(partials, nblk, out + B_ * C_);
}

// Round 2
// 1553.962 us; speedup vs baseline: 2.9826x; 2.9826x over previous
//
#include <hip/hip_runtime.h>
#include <hip/hip_bf16.h>

#define B_ 4
#define S_ 2048
#define E_ 100
#define F_ 64
#define C_ 8922
#define V_ 52000

// ---------------------------------------------------------------------------
// Kernel 1: embedding lookup + 4 'same' convs + tanh
// h layout: [branch][b][s][f]  (f contiguous)
// ---------------------------------------------------------------------------
__global__ __launch_bounds__(256) void conv_tanh_kernel(
    const int* __restrict__ x, const float* __restrict__ embed,
    const float* __restrict__ w3, const float* __restrict__ b3,
    const float* __restrict__ w5, const float* __restrict__ b5,
    const float* __restrict__ w7, const float* __restrict__ b7,
    const float* __restrict__ w9, const float* __restrict__ b9,
    float* __restrict__ h)
{
    __shared__ float xe[E_ * 40];   // [E][40] rows s0-4 .. s0+35 (halo 4 for k=9)

    const int blk = blockIdx.x;
    const int b   = blk / (S_ / 32);
    const int st  = blk % (S_ / 32);
    const int s0  = st * 32;
    const int t   = threadIdx.x;

    for (int idx = t; idx < E_ * 40; idx += 256) {
        const int e = idx / 40;
        const int r = idx - e * 40;
        const int s = s0 - 4 + r;
        float v = 0.f;
        if (s >= 0 && s < S_) {
            const int tok = x[b * S_ + s];
            v = embed[tok * E_ + e];
        }
        xe[e * 40 + r] = v;
    }
    __syncthreads();

    const int f      = t & 63;
    const int sg     = t >> 6;   // 0..3
    const int slbase = sg * 8;

    float acc3[8] = {0}, acc5[8] = {0}, acc7[8] = {0}, acc9[8] = {0};

    const float* __restrict__ w3f = w3 + f * E_ * 3;
    const float* __restrict__ w5f = w5 + f * E_ * 5;
    const float* __restrict__ w7f = w7 + f * E_ * 7;
    const float* __restrict__ w9f = w9 + f * E_ * 9;

    for (int e = 0; e < E_; ++e) {
        float win[16];
        const float* base = &xe[e * 40 + slbase];
        *(float4*)&win[0]  = *(const float4*)&base[0];
        *(float4*)&win[4]  = *(const float4*)&base[4];
        *(float4*)&win[8]  = *(const float4*)&base[8];
        *(float4*)&win[12] = *(const float4*)&base[12];

        float W3[3], W5[5], W7[7], W9[9];
        #pragma unroll
        for (int d = 0; d < 3; ++d) W3[d] = w3f[e * 3 + d];
        #pragma unroll
        for (int d = 0; d < 5; ++d) W5[d] = w5f[e * 5 + d];
        #pragma unroll
        for (int d = 0; d < 7; ++d) W7[d] = w7f[e * 7 + d];
        #pragma unroll
        for (int d = 0; d < 9; ++d) W9[d] = w9f[e * 9 + d];

        #pragma unroll
        for (int i = 0; i < 8; ++i) {
            #pragma unroll
            for (int d = 0; d < 3; ++d) acc3[i] = fmaf(win[i + d + 3], W3[d], acc3[i]);
            #pragma unroll
            for (int d = 0; d < 5; ++d) acc5[i] = fmaf(win[i + d + 2], W5[d], acc5[i]);
            #pragma unroll
            for (int d = 0; d < 7; ++d) acc7[i] = fmaf(win[i + d + 1], W7[d], acc7[i]);
            #pragma unroll
            for (int d = 0; d < 9; ++d) acc9[i] = fmaf(win[i + d + 0], W9[d], acc9[i]);
        }
    }

    const float bb3 = b3[f], bb5 = b5[f], bb7 = b7[f], bb9 = b9[f];
    #pragma unroll
    for (int i = 0; i < 8; ++i) {
        const int s = s0 + slbase + i;
        h[((0 * B_ + b) * S_ + s) * F_ + f] = tanhf(acc3[i] + bb3);
        h[((1 * B_ + b) * S_ + s) * F_ + f] = tanhf(acc5[i] + bb5);
        h[((2 * B_ + b) * S_ + s) * F_ + f] = tanhf(acc7[i] + bb7);
        h[((3 * B_ + b) * S_ + s) * F_ + f] = tanhf(acc9[i] + bb9);
    }
}

// ---------------------------------------------------------------------------
// Kernel 2: fused scores -> exp -> weighted sum, single pass, NO max-sub
// (|score| <= sum|U[c,:]| ~ 2.5 => exp overflow-safe in fp32; softmax result
//  is mathematically identical to the max-subtracted reference)
// grid: (ceil(C/64), B, 4branch*2chunk), 64 threads (1 wave), one c per lane
// Outputs per (br,b,chunk,c): pacc[64] = sum_s exp(sc)*h, pl = sum_s exp(sc)
// ---------------------------------------------------------------------------
__global__ __launch_bounds__(64, 2) void attn_kernel(
    const float* __restrict__ U3, const float* __restrict__ U5,
    const float* __restrict__ U7, const float* __restrict__ U9,
    const float* __restrict__ h, float* __restrict__ pacc, float* __restrict__ pl)
{
    __shared__ float hs[16 * F_];   // 4 KB: one 16-row tile

    const int lane = threadIdx.x;
    const int b    = blockIdx.y;
    const int br   = blockIdx.z >> 1;
    const int ch   = blockIdx.z & 1;
    const int c    = blockIdx.x * 64 + lane;
    const bool valid = (c < C_);

    const float* __restrict__ U =
        (br == 0) ? U3 : (br == 1) ? U5 : (br == 2) ? U7 : U9;
    const float* __restrict__ hb =
        h + ((size_t)(br * B_ + b) * S_ + ch * (S_ / 2)) * F_;

    float q[F_];
    if (valid) {
        const float4* qr = (const float4*)(U + (size_t)c * F_);
        #pragma unroll
        for (int i = 0; i < 16; ++i) *(float4*)&q[i * 4] = qr[i];
    } else {
        #pragma unroll
        for (int i = 0; i < F_; ++i) q[i] = 0.f;
    }

    float acc[F_];
    #pragma unroll
    for (int i = 0; i < F_; ++i) acc[i] = 0.f;
    float lsum = 0.f;

    // register-prefetch double buffering of the 4 KB tile (1 wave: 4 float4/lane)
    const float4* src = (const float4*)hb;
    float4 pre0 = src[lane], pre1 = src[64 + lane],
           pre2 = src[128 + lane], pre3 = src[192 + lane];

    const int NT = (S_ / 2) / 16;   // 64 tiles of 16 rows
    for (int t = 0; t < NT; ++t) {
        float4* dst = (float4*)hs;
        dst[lane] = pre0; dst[64 + lane] = pre1;
        dst[128 + lane] = pre2; dst[192 + lane] = pre3;
        __syncthreads();
        if (t < NT - 1) {
            const float4* ns = src + (t + 1) * 256;
            pre0 = ns[lane]; pre1 = ns[64 + lane];
            pre2 = ns[128 + lane]; pre3 = ns[192 + lane];
        }

        for (int j = 0; j < 16; ++j) {
            float rw[F_];
            #pragma unroll
            for (int i = 0; i < 16; ++i)
                *(float4*)&rw[i * 4] = *(const float4*)&hs[j * F_ + i * 4];

            float d0 = 0.f, d1 = 0.f, d2 = 0.f, d3 = 0.f;
            #pragma unroll
            for (int i = 0; i < 16; ++i) {
                d0 = fmaf(q[i * 4 + 0], rw[i * 4 + 0], d0);
                d1 = fmaf(q[i * 4 + 1], rw[i * 4 + 1], d1);
                d2 = fmaf(q[i * 4 + 2], rw[i * 4 + 2], d2);
                d3 = fmaf(q[i * 4 + 3], rw[i * 4 + 3], d3);
            }
            const float p = __expf((d0 + d1) + (d2 + d3));
            lsum += p;
            #pragma unroll
            for (int i = 0; i < F_; ++i) acc[i] = fmaf(p, rw[i], acc[i]);
        }
        __syncthreads();
    }

    if (valid) {
        const size_t base = ((size_t)((br * B_ + b) * 2 + ch) * C_ + c);
        float4* po = (float4*)(pacc + base * F_);
        #pragma unroll
        for (int i = 0; i < 16; ++i) {
            float4 v;
            v.x = acc[i * 4 + 0]; v.y = acc[i * 4 + 1];
            v.z = acc[i * 4 + 2]; v.w = acc[i * 4 + 3];
            po[i] = v;
        }
        pl[base] = lsum;
    }
}

// ---------------------------------------------------------------------------
// Kernel 3: merge S-chunks, y_hat = sum(Wf * m) + bf, BCE partials
// ---------------------------------------------------------------------------
__global__ __launch_bounds__(256) void final_kernel(
    const float* __restrict__ pacc, const float* __restrict__ pl,
    const float* __restrict__ Wf, const float* __restrict__ bf,
    const float* __restrict__ y, float* __restrict__ out,
    float* __restrict__ partials)
{
    const int p = blockIdx.x * 256 + threadIdx.x;
    float bce = 0.f;
    if (p < B_ * C_) {
        const int b = p / C_;
        const int c = p - b * C_;
        float a = 0.f;
        #pragma unroll
        for (int br = 0; br < 4; ++br) {
            const size_t base0 = ((size_t)((br * B_ + b) * 2 + 0) * C_ + c);
            const size_t base1 = ((size_t)((br * B_ + b) * 2 + 1) * C_ + c);
            const float inv = 1.f / (pl[base0] + pl[base1]);
            const float4* p0 = (const float4*)(pacc + base0 * F_);
            const float4* p1 = (const float4*)(pacc + base1 * F_);
            const float4* wr = (const float4*)(Wf + (size_t)c * (4 * F_) + br * F_);
            #pragma unroll
            for (int i = 0; i < 16; ++i) {
                const float4 v0 = p0[i], v1 = p1[i], w = wr[i];
                a = fmaf((v0.x + v1.x) * inv, w.x, a);
                a = fmaf((v0.y + v1.y) * inv, w.y, a);
                a = fmaf((v0.z + v1.z) * inv, w.z, a);
                a = fmaf((v0.w + v1.w) * inv, w.w, a);
            }
        }
        const float yh = a + bf[c];
        out[p] = yh;
        const float yy = y[p];
        bce = fmaxf(yh, 0.f) - yh * yy + log1pf(expf(-fabsf(yh)));
    }
    __shared__ float red[256];
    red[threadIdx.x] = bce;
    __syncthreads();
    #pragma unroll
    for (int stp = 128; stp > 0; stp >>= 1) {
        if (threadIdx.x < stp) red[threadIdx.x] += red[threadIdx.x + stp];
        __syncthreads();
    }
    if (threadIdx.x == 0) partials[blockIdx.x] = red[0];
}

__global__ __launch_bounds__(256) void loss_kernel(
    const float* __restrict__ partials, int n, float* __restrict__ out_loss)
{
    __shared__ float red[256];
    float v = (threadIdx.x < n) ? partials[threadIdx.x] : 0.f;
    red[threadIdx.x] = v;
    __syncthreads();
    #pragma unroll
    for (int stp = 128; stp > 0; stp >>= 1) {
        if (threadIdx.x < stp) red[threadIdx.x] += red[threadIdx.x + stp];
        __syncthreads();
    }
    if (threadIdx.x == 0) *out_loss = red[0] / (float)(B_ * C_);
}

// ---------------------------------------------------------------------------
extern "C" void kernel_launch(void* const* d_in, const int* in_sizes, int n_in,
                              void* d_out, int out_size, void* d_ws, size_t ws_size,
                              hipStream_t stream)
{
    const int*   x     = (const int*)  d_in[0];
    const float* y     = (const float*)d_in[1];
    const float* embed = (const float*)d_in[2];
    const float* w3    = (const float*)d_in[3];
    const float* b3    = (const float*)d_in[4];
    const float* w5    = (const float*)d_in[5];
    const float* b5    = (const float*)d_in[6];
    const float* w7    = (const float*)d_in[7];
    const float* b7    = (const float*)d_in[8];
    const float* w9    = (const float*)d_in[9];
    const float* b9    = (const float*)d_in[10];
    const float* U3    = (const float*)d_in[11];
    const float* U5    = (const float*)d_in[12];
    const float* U7    = (const float*)d_in[13];
    const float* U9    = (const float*)d_in[14];
    const float* Wf    = (const float*)d_in[15];
    const float* bfv   = (const float*)d_in[16];

    float* ws       = (float*)d_ws;
    float* h        = ws;                        // 4*B*S*F        = 2,097,152 f
    float* pacc     = h + 4 * B_ * S_ * F_;      // 4*B*2*C*F      = 18,264,576 f
    float* pl       = pacc + (size_t)4 * B_ * 2 * C_ * F_;   // 4*B*2*C = 285,504 f
    float* partials = pl + (size_t)4 * B_ * 2 * C_;          // 140 f
    float* out      = (float*)d_out;

    conv_tanh_kernel<<<B_ * (S_ / 32), 256, 0, stream>>>(
        x, embed, w3, b3, w5, b5, w7, b7, w9, b9, h);

    dim3 ag((C_ + 63) / 64, B_, 8);   // 140 x 4 x (4 branch * 2 S-chunk)
    attn_kernel<<<ag, 64, 0, stream>>>(U3, U5, U7, U9, h, pacc, pl);

    const int nblk = (B_ * C_ + 255) / 256;   // 140
    final_kernel<<<nblk, 256, 0, stream>>>(pacc, pl, Wf, bfv, y, out, partials);
    loss_kernel<<<1, 256, 0, stream>>>(partials, nblk, out + B_ * C_);
}

// Round 3
// 374.368 us; speedup vs baseline: 12.3803x; 4.1509x over previous
//
#include <hip/hip_runtime.h>
#include <hip/hip_bf16.h>

#define B_ 4
#define S_ 2048
#define E_ 100
#define F_ 64
#define C_ 8922
#define V_ 52000

typedef short bf16x8 __attribute__((ext_vector_type(8)));
typedef short s16x4  __attribute__((ext_vector_type(4)));
typedef float f32x4  __attribute__((ext_vector_type(4)));

#define MFMA16(A, B, C) __builtin_amdgcn_mfma_f32_16x16x32_bf16(A, B, C, 0, 0, 0)

__device__ inline short bfb(float x) {
    __hip_bfloat16 h = __float2bfloat16(x);
    return *reinterpret_cast<short*>(&h);
}

// ---------------------------------------------------------------------------
// Kernel 1: embedding + 4 'same' convs + tanh -> TWO bf16 global layouts:
//  hk: per (br,b,s-chunk32): row-major [32][64] bf16 with byte XOR-swizzle
//      lin_b = (sl*128 + f*2) ^ ((sl&7)<<4)        (G4 bank-conflict fix)
//  hv: per (br,b,s-chunk32): tr-read subtiles
//      lin = (f>>4)*512 + ((sl>>4)&1)*256 + ((sl>>2)&3)*64 + (sl&3)*16 + (f&15)
// Both staged to LDS as LINEAR 4KB copies (global_load_lds-compatible).
// ---------------------------------------------------------------------------
__device__ inline void store_h(char* hkB, char* hvB, int b, int br2, int s,
                               int f, float val) {
    const unsigned short u = (unsigned short)bfb(val);
    const size_t cb = ((size_t)(br2 * 4 + b) * 64 + (s >> 5)) * 4096;
    const int sl = s & 31;
    const unsigned ok = ((unsigned)(sl * 128 + f * 2)) ^ ((unsigned)(sl & 7) << 4);
    *(unsigned short*)(hkB + cb + ok) = u;
    const unsigned ov = (unsigned)(((f >> 4) * 512 + ((sl >> 4) & 1) * 256 +
                                    ((sl >> 2) & 3) * 64 + (sl & 3) * 16 +
                                    (f & 15)) * 2);
    *(unsigned short*)(hvB + cb + ov) = u;
}

__global__ __launch_bounds__(256) void conv_tanh_kernel(
    const int* __restrict__ x, const float* __restrict__ embed,
    const float* __restrict__ w3, const float* __restrict__ b3,
    const float* __restrict__ w5, const float* __restrict__ b5,
    const float* __restrict__ w7, const float* __restrict__ b7,
    const float* __restrict__ w9, const float* __restrict__ b9,
    char* __restrict__ hkB, char* __restrict__ hvB)
{
    __shared__ float xe[E_ * 40];   // [E][40] rows s0-4 .. s0+35 (halo 4 for k=9)

    const int blk = blockIdx.x;
    const int b   = blk / (S_ / 32);
    const int st  = blk % (S_ / 32);
    const int s0  = st * 32;
    const int t   = threadIdx.x;

    for (int idx = t; idx < E_ * 40; idx += 256) {
        const int e = idx / 40;
        const int r = idx - e * 40;
        const int s = s0 - 4 + r;
        float v = 0.f;
        if (s >= 0 && s < S_) {
            const int tok = x[b * S_ + s];
            v = embed[tok * E_ + e];
        }
        xe[e * 40 + r] = v;
    }
    __syncthreads();

    const int f      = t & 63;
    const int sg     = t >> 6;
    const int slbase = sg * 8;

    float acc3[8] = {0}, acc5[8] = {0}, acc7[8] = {0}, acc9[8] = {0};

    const float* __restrict__ w3f = w3 + f * E_ * 3;
    const float* __restrict__ w5f = w5 + f * E_ * 5;
    const float* __restrict__ w7f = w7 + f * E_ * 7;
    const float* __restrict__ w9f = w9 + f * E_ * 9;

    for (int e = 0; e < E_; ++e) {
        float win[16];
        const float* base = &xe[e * 40 + slbase];
        *(float4*)&win[0]  = *(const float4*)&base[0];
        *(float4*)&win[4]  = *(const float4*)&base[4];
        *(float4*)&win[8]  = *(const float4*)&base[8];
        *(float4*)&win[12] = *(const float4*)&base[12];

        float W3[3], W5[5], W7[7], W9[9];
        #pragma unroll
        for (int d = 0; d < 3; ++d) W3[d] = w3f[e * 3 + d];
        #pragma unroll
        for (int d = 0; d < 5; ++d) W5[d] = w5f[e * 5 + d];
        #pragma unroll
        for (int d = 0; d < 7; ++d) W7[d] = w7f[e * 7 + d];
        #pragma unroll
        for (int d = 0; d < 9; ++d) W9[d] = w9f[e * 9 + d];

        #pragma unroll
        for (int i = 0; i < 8; ++i) {
            #pragma unroll
            for (int d = 0; d < 3; ++d) acc3[i] = fmaf(win[i + d + 3], W3[d], acc3[i]);
            #pragma unroll
            for (int d = 0; d < 5; ++d) acc5[i] = fmaf(win[i + d + 2], W5[d], acc5[i]);
            #pragma unroll
            for (int d = 0; d < 7; ++d) acc7[i] = fmaf(win[i + d + 1], W7[d], acc7[i]);
            #pragma unroll
            for (int d = 0; d < 9; ++d) acc9[i] = fmaf(win[i + d + 0], W9[d], acc9[i]);
        }
    }

    const float bb3 = b3[f], bb5 = b5[f], bb7 = b7[f], bb9 = b9[f];
    #pragma unroll
    for (int i = 0; i < 8; ++i) {
        const int s = s0 + slbase + i;
        store_h(hkB, hvB, b, 0, s, f, tanhf(acc3[i] + bb3));
        store_h(hkB, hvB, b, 1, s, f, tanhf(acc5[i] + bb5));
        store_h(hkB, hvB, b, 2, s, f, tanhf(acc7[i] + bb7));
        store_h(hkB, hvB, b, 3, s, f, tanhf(acc9[i] + bb9));
    }
}

// ---------------------------------------------------------------------------
// Kernel 2: bf16 MFMA flash attention (no max-sub; scores bounded ~±2.5).
// Block: 256 thr (4 waves), 256 c's (64 per wave). Loop 64 chunks of 32 s.
// Swapped QK^T: A=K (M=s), B=Q (N=c) => lane holds P rows for c=lane&15.
// PV: A=P (M=c), B=V via ds_read_b64_tr_b16 with matching sigma k-map.
// mten out: [br][b][c][f] fp32, softmax applied.
// ---------------------------------------------------------------------------
#define TRREAD(dst, off) \
    asm volatile("ds_read_b64_tr_b16 %0, %1 offset:" #off \
                 : "=v"(dst) : "v"(vaddr));

typedef const __attribute__((address_space(1))) unsigned int* as1_u32p;
typedef __attribute__((address_space(3))) unsigned int* as3_u32p;

__device__ inline void gl_lds16(const void* g, unsigned lds_off) {
    __builtin_amdgcn_global_load_lds((as1_u32p)(uintptr_t)g,
                                     (as3_u32p)(uintptr_t)lds_off, 16, 0, 0);
}

__global__ __launch_bounds__(256, 2) void attn_mfma_kernel(
    const float* __restrict__ U3, const float* __restrict__ U5,
    const float* __restrict__ U7, const float* __restrict__ U9,
    const char* __restrict__ hkG, const char* __restrict__ hvG,
    float* __restrict__ mten)
{
    __shared__ unsigned short Kbuf[2][2048];   // 2 x 4KB (32s x 64f, XOR-swz)
    __shared__ unsigned short Vbuf[2][2048];   // 2 x 4KB (tr-subtiled)
    __shared__ float ls_lds[4][64];

    const int tid  = threadIdx.x;
    const int wave = tid >> 6;
    const int lane = tid & 63;
    const int g    = lane >> 4;
    const int lr   = lane & 15;

    const int b  = blockIdx.y;
    const int br = blockIdx.z;
    const int c0 = blockIdx.x * 256 + wave * 64;

    const float* __restrict__ U =
        (br == 0) ? U3 : (br == 1) ? U5 : (br == 2) ? U7 : U9;

    // ---- preload Q fragments (loop-invariant): Qf[cs][kh]
    bf16x8 Qf[4][2];
    #pragma unroll
    for (int cs = 0; cs < 4; ++cs) {
        int c = c0 + cs * 16 + lr;
        if (c > C_ - 1) c = C_ - 1;
        const float* Uc = U + (size_t)c * F_;
        #pragma unroll
        for (int kh = 0; kh < 2; ++kh) {
            const float4 lo = *(const float4*)(Uc + 32 * kh + 4 * g);
            const float4 hi = *(const float4*)(Uc + 32 * kh + 16 + 4 * g);
            bf16x8 q;
            q[0] = bfb(lo.x); q[1] = bfb(lo.y); q[2] = bfb(lo.z); q[3] = bfb(lo.w);
            q[4] = bfb(hi.x); q[5] = bfb(hi.y); q[6] = bfb(hi.z); q[7] = bfb(hi.w);
            Qf[cs][kh] = q;
        }
    }

    f32x4 acc[4][4];
    #pragma unroll
    for (int cs = 0; cs < 4; ++cs)
        #pragma unroll
        for (int fs = 0; fs < 4; ++fs)
            acc[cs][fs] = (f32x4){0.f, 0.f, 0.f, 0.f};
    float lsum[4] = {0.f, 0.f, 0.f, 0.f};

    const char* hkB = hkG + (size_t)((br * 4 + b) * 64) * 4096;
    const char* hvB = hvG + (size_t)((br * 4 + b) * 64) * 4096;
    const unsigned kL0 = (unsigned)(uintptr_t)&Kbuf[0][0];
    const unsigned vL0 = (unsigned)(uintptr_t)&Vbuf[0][0];

    // prologue: stage chunk 0 into buffer 0
    {
        const size_t go = (size_t)wave * 1024 + (size_t)(lane << 4);
        gl_lds16(hkB + go, kL0 + wave * 1024);
        gl_lds16(hvB + go, vL0 + wave * 1024);
    }
    __syncthreads();

    const unsigned xr = ((unsigned)(lr & 7)) << 4;

    for (int t = 0; t < 64; ++t) {
        const int cur = t & 1;
        if (t < 63) {
            const size_t go = (size_t)(t + 1) * 4096 + (size_t)wave * 1024 +
                              (size_t)(lane << 4);
            const unsigned lo = (unsigned)((cur ^ 1) * 4096 + wave * 1024);
            gl_lds16(hkB + go, kL0 + lo);
            gl_lds16(hvB + go, vL0 + lo);
        }

        // ---- K fragments: Kf[sh][kh]  (A-operand, rows = s)
        const char* Kb = (const char*)Kbuf + cur * 4096;
        bf16x8 Kf[2][2];
        #pragma unroll
        for (int sh = 0; sh < 2; ++sh) {
            const unsigned rowb = (unsigned)((16 * sh + lr) * 128);
            #pragma unroll
            for (int kh = 0; kh < 2; ++kh) {
                const unsigned f1 = ((unsigned)(kh * 64 + g * 8)) ^ xr;
                const unsigned f2 = ((unsigned)(kh * 64 + g * 8 + 32)) ^ xr;
                const s16x4 lo = *(const s16x4*)(Kb + rowb + f1);
                const s16x4 hi = *(const s16x4*)(Kb + rowb + f2);
                Kf[sh][kh] = __builtin_shufflevector(lo, hi, 0, 1, 2, 3, 4, 5, 6, 7);
            }
        }

        // ---- V fragments via hardware transpose-read (stride-32B gather)
        const unsigned vaddr = vL0 + (unsigned)(cur * 4096 + g * 128 + lr * 2);
        s16x4 va0, va1, vb0, vb1, vc0, vc1, vd0, vd1;
        TRREAD(va0, 0)    TRREAD(va1, 512)
        TRREAD(vb0, 1024) TRREAD(vb1, 1536)
        TRREAD(vc0, 2048) TRREAD(vc1, 2560)
        TRREAD(vd0, 3072) TRREAD(vd1, 3584)
        asm volatile("s_waitcnt lgkmcnt(0)" ::: "memory");
        __builtin_amdgcn_sched_barrier(0);

        bf16x8 Vf[4];
        Vf[0] = __builtin_shufflevector(va0, va1, 0, 1, 2, 3, 4, 5, 6, 7);
        Vf[1] = __builtin_shufflevector(vb0, vb1, 0, 1, 2, 3, 4, 5, 6, 7);
        Vf[2] = __builtin_shufflevector(vc0, vc1, 0, 1, 2, 3, 4, 5, 6, 7);
        Vf[3] = __builtin_shufflevector(vd0, vd1, 0, 1, 2, 3, 4, 5, 6, 7);

        // ---- scores -> exp -> P frags; then PV
        bf16x8 Pf[4];
        #pragma unroll
        for (int cs = 0; cs < 4; ++cs) {
            f32x4 d0 = (f32x4){0.f, 0.f, 0.f, 0.f};
            f32x4 d1 = (f32x4){0.f, 0.f, 0.f, 0.f};
            d0 = MFMA16(Kf[0][0], Qf[cs][0], d0);
            d0 = MFMA16(Kf[0][1], Qf[cs][1], d0);
            d1 = MFMA16(Kf[1][0], Qf[cs][0], d1);
            d1 = MFMA16(Kf[1][1], Qf[cs][1], d1);
            f32x4 p0, p1;
            #pragma unroll
            for (int r = 0; r < 4; ++r) { p0[r] = __expf(d0[r]); p1[r] = __expf(d1[r]); }
            lsum[cs] += (p0[0] + p0[1] + p0[2] + p0[3]) +
                        (p1[0] + p1[1] + p1[2] + p1[3]);
            bf16x8 pf;
            #pragma unroll
            for (int r = 0; r < 4; ++r) { pf[r] = bfb(p0[r]); pf[4 + r] = bfb(p1[r]); }
            Pf[cs] = pf;
        }

        #pragma unroll
        for (int cs = 0; cs < 4; ++cs)
            #pragma unroll
            for (int fs = 0; fs < 4; ++fs)
                acc[cs][fs] = MFMA16(Pf[cs], Vf[fs], acc[cs][fs]);

        __syncthreads();   // drains vmcnt(0): next buffer staged; cur reads done
    }

    // ---- softmax denominators: reduce over lane-groups, share via LDS
    #pragma unroll
    for (int cs = 0; cs < 4; ++cs) {
        lsum[cs] += __shfl_xor(lsum[cs], 16);
        lsum[cs] += __shfl_xor(lsum[cs], 32);
        if (g == 0) ls_lds[wave][cs * 16 + lr] = lsum[cs];
    }
    __syncthreads();

    #pragma unroll
    for (int cs = 0; cs < 4; ++cs) {
        f32x4 linv;
        #pragma unroll
        for (int r = 0; r < 4; ++r)
            linv[r] = 1.f / ls_lds[wave][cs * 16 + 4 * g + r];
        #pragma unroll
        for (int fs = 0; fs < 4; ++fs) {
            #pragma unroll
            for (int r = 0; r < 4; ++r) {
                const int c = c0 + cs * 16 + 4 * g + r;
                if (c < C_)
                    mten[((size_t)(br * 4 + b) * C_ + c) * F_ + fs * 16 + lr] =
                        acc[cs][fs][r] * linv[r];
            }
        }
    }
}

// ---------------------------------------------------------------------------
// Kernel 3: y_hat = sum(Wf * concat(m)) + bf ; per-block BCE partials
// ---------------------------------------------------------------------------
__global__ __launch_bounds__(256) void final_kernel(
    const float* __restrict__ mten, const float* __restrict__ Wf,
    const float* __restrict__ bf, const float* __restrict__ y,
    float* __restrict__ out, float* __restrict__ partials)
{
    const int p = blockIdx.x * 256 + threadIdx.x;
    float bce = 0.f;
    if (p < B_ * C_) {
        const int b = p / C_;
        const int c = p - b * C_;
        float a0 = 0.f, a1 = 0.f, a2 = 0.f, a3 = 0.f;
        #pragma unroll
        for (int br = 0; br < 4; ++br) {
            const float4* mr = (const float4*)(mten + ((size_t)(br * 4 + b) * C_ + c) * F_);
            const float4* wr = (const float4*)(Wf + (size_t)c * (4 * F_) + br * F_);
            #pragma unroll
            for (int i = 0; i < 16; i += 4) {
                const float4 m0 = mr[i + 0], w0 = wr[i + 0];
                const float4 m1 = mr[i + 1], w1 = wr[i + 1];
                const float4 m2 = mr[i + 2], w2 = wr[i + 2];
                const float4 m3 = mr[i + 3], w3v = wr[i + 3];
                a0 = fmaf(m0.x, w0.x, a0); a0 = fmaf(m0.y, w0.y, a0);
                a0 = fmaf(m0.z, w0.z, a0); a0 = fmaf(m0.w, w0.w, a0);
                a1 = fmaf(m1.x, w1.x, a1); a1 = fmaf(m1.y, w1.y, a1);
                a1 = fmaf(m1.z, w1.z, a1); a1 = fmaf(m1.w, w1.w, a1);
                a2 = fmaf(m2.x, w2.x, a2); a2 = fmaf(m2.y, w2.y, a2);
                a2 = fmaf(m2.z, w2.z, a2); a2 = fmaf(m2.w, w2.w, a2);
                a3 = fmaf(m3.x, w3v.x, a3); a3 = fmaf(m3.y, w3v.y, a3);
                a3 = fmaf(m3.z, w3v.z, a3); a3 = fmaf(m3.w, w3v.w, a3);
            }
        }
        const float yh = (a0 + a1) + (a2 + a3) + bf[c];
        out[p] = yh;
        const float yy = y[p];
        bce = fmaxf(yh, 0.f) - yh * yy + log1pf(expf(-fabsf(yh)));
    }
    __shared__ float red[256];
    red[threadIdx.x] = bce;
    __syncthreads();
    #pragma unroll
    for (int stp = 128; stp > 0; stp >>= 1) {
        if (threadIdx.x < stp) red[threadIdx.x] += red[threadIdx.x + stp];
        __syncthreads();
    }
    if (threadIdx.x == 0) partials[blockIdx.x] = red[0];
}

__global__ __launch_bounds__(256) void loss_kernel(
    const float* __restrict__ partials, int n, float* __restrict__ out_loss)
{
    __shared__ float red[256];
    float v = (threadIdx.x < n) ? partials[threadIdx.x] : 0.f;
    red[threadIdx.x] = v;
    __syncthreads();
    #pragma unroll
    for (int stp = 128; stp > 0; stp >>= 1) {
        if (threadIdx.x < stp) red[threadIdx.x] += red[threadIdx.x + stp];
        __syncthreads();
    }
    if (threadIdx.x == 0) *out_loss = red[0] / (float)(B_ * C_);
}

// ---------------------------------------------------------------------------
extern "C" void kernel_launch(void* const* d_in, const int* in_sizes, int n_in,
                              void* d_out, int out_size, void* d_ws, size_t ws_size,
                              hipStream_t stream)
{
    const int*   x     = (const int*)  d_in[0];
    const float* y     = (const float*)d_in[1];
    const float* embed = (const float*)d_in[2];
    const float* w3    = (const float*)d_in[3];
    const float* b3    = (const float*)d_in[4];
    const float* w5    = (const float*)d_in[5];
    const float* b5    = (const float*)d_in[6];
    const float* w7    = (const float*)d_in[7];
    const float* b7    = (const float*)d_in[8];
    const float* w9    = (const float*)d_in[9];
    const float* b9    = (const float*)d_in[10];
    const float* U3    = (const float*)d_in[11];
    const float* U5    = (const float*)d_in[12];
    const float* U7    = (const float*)d_in[13];
    const float* U9    = (const float*)d_in[14];
    const float* Wf    = (const float*)d_in[15];
    const float* bfv   = (const float*)d_in[16];

    float* ws       = (float*)d_ws;
    float* mten     = ws;                                  // 9,136,128 f
    char*  hkB      = (char*)(ws + (size_t)4 * B_ * C_ * F_);  // 4 MB bf16
    char*  hvB      = hkB + (size_t)16 * 64 * 4096;            // 4 MB bf16
    float* partials = (float*)(hvB + (size_t)16 * 64 * 4096); // 140 f
    float* out      = (float*)d_out;

    conv_tanh_kernel<<<B_ * (S_ / 32), 256, 0, stream>>>(
        x, embed, w3, b3, w5, b5, w7, b7, w9, b9, hkB, hvB);

    dim3 ag((C_ + 255) / 256, B_, 4);   // 35 x 4 x 4
    attn_mfma_kernel<<<ag, 256, 0, stream>>>(U3, U5, U7, U9, hkB, hvB, mten);

    const int nblk = (B_ * C_ + 255) / 256;   // 140
    final_kernel<<<nblk, 256, 0, stream>>>(mten, Wf, bfv, y, out, partials);
    loss_kernel<<<1, 256, 0, stream>>>(partials, nblk, out + B_ * C_);
}

// Round 4
// 257.582 us; speedup vs baseline: 17.9934x; 1.4534x over previous
//
#include <hip/hip_runtime.h>
#include <hip/hip_bf16.h>

#define B_ 4
#define S_ 2048
#define E_ 100
#define F_ 64
#define C_ 8922
#define V_ 52000

typedef short bf16x8 __attribute__((ext_vector_type(8)));
typedef short s16x4  __attribute__((ext_vector_type(4)));
typedef float f32x4  __attribute__((ext_vector_type(4)));

#define MFMA16(A, B, C) __builtin_amdgcn_mfma_f32_16x16x32_bf16(A, B, C, 0, 0, 0)

__device__ inline short bfb(float x) {
    __hip_bfloat16 h = __float2bfloat16(x);
    return *reinterpret_cast<short*>(&h);
}

// ---------------------------------------------------------------------------
// Kernel 0: weight prepack (per-lane MFMA B-fragments) + zero yhat.
// W[d][e][brf]: all 4 branch kernels zero-padded to k=9 (d = d' + 3 - br),
// e padded 100->128 with zeros. Packed so conv's B-frag is ONE dwordx4:
//   Wp[(((step)*16 + nt)*64 + lane)*8 + j],  step = d*4+ec,
//   k(g,j) = g*4 + (j&3) + ((j>>2)<<4),  e = ec*32 + k,  n = nt*16 + lr.
// ---------------------------------------------------------------------------
__global__ __launch_bounds__(256) void prep_kernel(
    const float* __restrict__ w3, const float* __restrict__ w5,
    const float* __restrict__ w7, const float* __restrict__ w9,
    unsigned short* __restrict__ Wp, float* __restrict__ yhat)
{
    const int gid = blockIdx.x * 256 + threadIdx.x;   // 0..294911
    if (gid < B_ * C_) yhat[gid] = 0.f;

    const int j    = gid & 7;
    const int lane = (gid >> 3) & 63;
    const int nt   = (gid >> 9) & 15;
    const int step = gid >> 13;          // 0..35
    const int d    = step >> 2;
    const int ec   = step & 3;
    const int g    = lane >> 4;
    const int lr   = lane & 15;
    const int k    = g * 4 + (j & 3) + ((j >> 2) << 4);
    const int e    = ec * 32 + k;
    const int n    = nt * 16 + lr;
    const int br   = n >> 6;
    const int f    = n & 63;
    const int kb   = 3 + 2 * br;
    const int dp   = d - (3 - br);       // 3-br == 4 - kb/2

    float val = 0.f;
    if (e < E_ && dp >= 0 && dp < kb) {
        const float* w = (br == 0) ? w3 : (br == 1) ? w5 : (br == 2) ? w7 : w9;
        val = w[((size_t)f * E_ + e) * kb + dp];
    }
    Wp[gid] = (unsigned short)bfb(val);
}

// ---------------------------------------------------------------------------
// h bf16 global layouts for the attention kernel (verified in R3):
//  hk: per (br,b,s-chunk32): [32][64] bf16, byte XOR-swizzle ((sl&7)<<4)
//  hv: per (br,b,s-chunk32): tr-read subtiles
// ---------------------------------------------------------------------------
__device__ inline void store_h(char* hkB, char* hvB, int b, int br2, int s,
                               int f, float val) {
    const unsigned short u = (unsigned short)bfb(val);
    const size_t cb = ((size_t)(br2 * 4 + b) * 64 + (s >> 5)) * 4096;
    const int sl = s & 31;
    const unsigned ok = ((unsigned)(sl * 128 + f * 2)) ^ ((unsigned)(sl & 7) << 4);
    *(unsigned short*)(hkB + cb + ok) = u;
    const unsigned ov = (unsigned)(((f >> 4) * 512 + ((sl >> 4) & 1) * 256 +
                                    ((sl >> 2) & 3) * 64 + (sl & 3) * 16 +
                                    (f & 15)) * 2);
    *(unsigned short*)(hvB + cb + ov) = u;
}

// ---------------------------------------------------------------------------
// Kernel 1: conv as MFMA GEMM. Block = 32-s tile (+4 halo each side), 4 waves;
// wave w computes [32 s] x [64 f] for branch br=w. K-loop: 36 steps (9 d-shifts
// x 4 e-chunks of 32). A = xe tile from LDS (XOR-swizzled bf16), B = Wp frags
// straight from global (L2). Epilogue: +bias, tanh, store_h.
// ---------------------------------------------------------------------------
__global__ __launch_bounds__(256, 1) void conv_mfma_kernel(
    const int* __restrict__ x, const float* __restrict__ embed,
    const unsigned short* __restrict__ Wp,
    const float* __restrict__ b3, const float* __restrict__ b5,
    const float* __restrict__ b7, const float* __restrict__ b9,
    char* __restrict__ hkB, char* __restrict__ hvB)
{
    __shared__ unsigned short xeT[40 * 128];   // [row][e] bf16, swizzled, 10 KB

    const int blk  = blockIdx.x;
    const int b    = blk >> 6;
    const int st   = blk & 63;
    const int s0   = st * 32;
    const int tid  = threadIdx.x;
    const int wave = tid >> 6;
    const int lane = tid & 63;
    const int g    = lane >> 4;
    const int lr   = lane & 15;

    // ---- stage xe: 40 rows x 128 e (row = s0-4+row; e>=100 and OOB rows = 0)
    for (int task = tid; task < 640; task += 256) {
        const int row = task >> 4;
        const int o   = task & 15;      // e-octet
        const int s   = s0 - 4 + row;
        float v[8];
        #pragma unroll
        for (int i = 0; i < 8; ++i) v[i] = 0.f;
        if (s >= 0 && s < S_ && o < 13) {
            const int tok = x[b * S_ + s];
            const float* er = embed + (size_t)tok * E_ + o * 8;
            if (o < 12) {
                #pragma unroll
                for (int i = 0; i < 8; ++i) v[i] = er[i];
            } else {
                v[0] = er[0]; v[1] = er[1]; v[2] = er[2]; v[3] = er[3];
            }
        }
        unsigned short u[8];
        #pragma unroll
        for (int i = 0; i < 8; ++i) u[i] = (unsigned short)bfb(v[i]);
        const unsigned xr = ((unsigned)(row & 15)) << 3;
        char* base = (char*)xeT + row * 256;
        *(uint2*)(base + (((unsigned)(o * 16)) ^ xr))     = *(const uint2*)&u[0];
        *(uint2*)(base + (((unsigned)(o * 16 + 8)) ^ xr)) = *(const uint2*)&u[4];
    }
    __syncthreads();

    f32x4 acc[2][4];
    #pragma unroll
    for (int m2 = 0; m2 < 2; ++m2)
        #pragma unroll
        for (int ns = 0; ns < 4; ++ns)
            acc[m2][ns] = (f32x4){0.f, 0.f, 0.f, 0.f};

    const char* xb = (const char*)xeT;
    #pragma unroll
    for (int step = 0; step < 36; ++step) {
        const int d  = step >> 2;
        const int ec = step & 3;

        bf16x8 Af[2];
        #pragma unroll
        for (int m2 = 0; m2 < 2; ++m2) {
            const int row = m2 * 16 + lr + d;
            const unsigned xr = ((unsigned)(row & 15)) << 3;
            const unsigned rb = (unsigned)row * 256;
            const unsigned e0 = (unsigned)(ec * 64 + g * 8);
            const s16x4 lo = *(const s16x4*)(xb + rb + (e0 ^ xr));
            const s16x4 hi = *(const s16x4*)(xb + rb + ((e0 + 32) ^ xr));
            Af[m2] = __builtin_shufflevector(lo, hi, 0, 1, 2, 3, 4, 5, 6, 7);
        }

        bf16x8 Bf[4];
        #pragma unroll
        for (int ns = 0; ns < 4; ++ns)
            Bf[ns] = *(const bf16x8*)(Wp +
                     (((size_t)step * 16 + wave * 4 + ns) * 64 + lane) * 8);

        #pragma unroll
        for (int m2 = 0; m2 < 2; ++m2)
            #pragma unroll
            for (int ns = 0; ns < 4; ++ns)
                acc[m2][ns] = MFMA16(Af[m2], Bf[ns], acc[m2][ns]);
    }

    // ---- epilogue: bias + tanh + store both layouts
    const float* bias = (wave == 0) ? b3 : (wave == 1) ? b5 : (wave == 2) ? b7 : b9;
    float bia[4];
    #pragma unroll
    for (int ns = 0; ns < 4; ++ns) bia[ns] = bias[ns * 16 + lr];

    #pragma unroll
    for (int m2 = 0; m2 < 2; ++m2)
        #pragma unroll
        for (int ns = 0; ns < 4; ++ns)
            #pragma unroll
            for (int r = 0; r < 4; ++r) {
                const int s = s0 + m2 * 16 + 4 * g + r;
                const int f = ns * 16 + lr;
                store_h(hkB, hvB, b, wave, s, f,
                        tanhf(acc[m2][ns][r] + bia[ns]));
            }
}

// ---------------------------------------------------------------------------
// Kernel 2: bf16 MFMA flash attention (no max-sub; scores bounded ~±2.5),
// with FUSED Wf epilogue: y_partial(b,c) += sum_f (acc_f/lsum)*Wf[c,br*64+f]
// via in-lane fs-dot + 16-lane shfl reduce + one atomicAdd per (c, br).
// ---------------------------------------------------------------------------
#define TRREAD(dst, off) \
    asm volatile("ds_read_b64_tr_b16 %0, %1 offset:" #off \
                 : "=v"(dst) : "v"(vaddr));

typedef const __attribute__((address_space(1))) unsigned int* as1_u32p;
typedef __attribute__((address_space(3))) unsigned int* as3_u32p;

__device__ inline void gl_lds16(const void* g, unsigned lds_off) {
    __builtin_amdgcn_global_load_lds((as1_u32p)(uintptr_t)g,
                                     (as3_u32p)(uintptr_t)lds_off, 16, 0, 0);
}

__global__ __launch_bounds__(256, 2) void attn_mfma_kernel(
    const float* __restrict__ U3, const float* __restrict__ U5,
    const float* __restrict__ U7, const float* __restrict__ U9,
    const char* __restrict__ hkG, const char* __restrict__ hvG,
    const float* __restrict__ Wf, float* __restrict__ yhat)
{
    __shared__ unsigned short Kbuf[2][2048];   // 2 x 4KB (32s x 64f, XOR-swz)
    __shared__ unsigned short Vbuf[2][2048];   // 2 x 4KB (tr-subtiled)
    __shared__ float ls_lds[4][64];

    const int tid  = threadIdx.x;
    const int wave = tid >> 6;
    const int lane = tid & 63;
    const int g    = lane >> 4;
    const int lr   = lane & 15;

    const int b  = blockIdx.y;
    const int br = blockIdx.z;
    const int c0 = blockIdx.x * 256 + wave * 64;

    const float* __restrict__ U =
        (br == 0) ? U3 : (br == 1) ? U5 : (br == 2) ? U7 : U9;

    // ---- preload Q fragments (loop-invariant): Qf[cs][kh]
    bf16x8 Qf[4][2];
    #pragma unroll
    for (int cs = 0; cs < 4; ++cs) {
        int c = c0 + cs * 16 + lr;
        if (c > C_ - 1) c = C_ - 1;
        const float* Uc = U + (size_t)c * F_;
        #pragma unroll
        for (int kh = 0; kh < 2; ++kh) {
            const float4 lo = *(const float4*)(Uc + 32 * kh + 4 * g);
            const float4 hi = *(const float4*)(Uc + 32 * kh + 16 + 4 * g);
            bf16x8 q;
            q[0] = bfb(lo.x); q[1] = bfb(lo.y); q[2] = bfb(lo.z); q[3] = bfb(lo.w);
            q[4] = bfb(hi.x); q[5] = bfb(hi.y); q[6] = bfb(hi.z); q[7] = bfb(hi.w);
            Qf[cs][kh] = q;
        }
    }

    f32x4 acc[4][4];
    #pragma unroll
    for (int cs = 0; cs < 4; ++cs)
        #pragma unroll
        for (int fs = 0; fs < 4; ++fs)
            acc[cs][fs] = (f32x4){0.f, 0.f, 0.f, 0.f};
    float lsum[4] = {0.f, 0.f, 0.f, 0.f};

    const char* hkB = hkG + (size_t)((br * 4 + b) * 64) * 4096;
    const char* hvB = hvG + (size_t)((br * 4 + b) * 64) * 4096;
    const unsigned kL0 = (unsigned)(uintptr_t)&Kbuf[0][0];
    const unsigned vL0 = (unsigned)(uintptr_t)&Vbuf[0][0];

    {
        const size_t go = (size_t)wave * 1024 + (size_t)(lane << 4);
        gl_lds16(hkB + go, kL0 + wave * 1024);
        gl_lds16(hvB + go, vL0 + wave * 1024);
    }
    __syncthreads();

    const unsigned xr = ((unsigned)(lr & 7)) << 4;

    for (int t = 0; t < 64; ++t) {
        const int cur = t & 1;
        if (t < 63) {
            const size_t go = (size_t)(t + 1) * 4096 + (size_t)wave * 1024 +
                              (size_t)(lane << 4);
            const unsigned lo = (unsigned)((cur ^ 1) * 4096 + wave * 1024);
            gl_lds16(hkB + go, kL0 + lo);
            gl_lds16(hvB + go, vL0 + lo);
        }

        const char* Kb = (const char*)Kbuf + cur * 4096;
        bf16x8 Kf[2][2];
        #pragma unroll
        for (int sh = 0; sh < 2; ++sh) {
            const unsigned rowb = (unsigned)((16 * sh + lr) * 128);
            #pragma unroll
            for (int kh = 0; kh < 2; ++kh) {
                const unsigned f1 = ((unsigned)(kh * 64 + g * 8)) ^ xr;
                const unsigned f2 = ((unsigned)(kh * 64 + g * 8 + 32)) ^ xr;
                const s16x4 lo = *(const s16x4*)(Kb + rowb + f1);
                const s16x4 hi = *(const s16x4*)(Kb + rowb + f2);
                Kf[sh][kh] = __builtin_shufflevector(lo, hi, 0, 1, 2, 3, 4, 5, 6, 7);
            }
        }

        const unsigned vaddr = vL0 + (unsigned)(cur * 4096 + g * 128 + lr * 2);
        s16x4 va0, va1, vb0, vb1, vc0, vc1, vd0, vd1;
        TRREAD(va0, 0)    TRREAD(va1, 512)
        TRREAD(vb0, 1024) TRREAD(vb1, 1536)
        TRREAD(vc0, 2048) TRREAD(vc1, 2560)
        TRREAD(vd0, 3072) TRREAD(vd1, 3584)
        asm volatile("s_waitcnt lgkmcnt(0)" ::: "memory");
        __builtin_amdgcn_sched_barrier(0);

        bf16x8 Vf[4];
        Vf[0] = __builtin_shufflevector(va0, va1, 0, 1, 2, 3, 4, 5, 6, 7);
        Vf[1] = __builtin_shufflevector(vb0, vb1, 0, 1, 2, 3, 4, 5, 6, 7);
        Vf[2] = __builtin_shufflevector(vc0, vc1, 0, 1, 2, 3, 4, 5, 6, 7);
        Vf[3] = __builtin_shufflevector(vd0, vd1, 0, 1, 2, 3, 4, 5, 6, 7);

        bf16x8 Pf[4];
        #pragma unroll
        for (int cs = 0; cs < 4; ++cs) {
            f32x4 d0 = (f32x4){0.f, 0.f, 0.f, 0.f};
            f32x4 d1 = (f32x4){0.f, 0.f, 0.f, 0.f};
            d0 = MFMA16(Kf[0][0], Qf[cs][0], d0);
            d0 = MFMA16(Kf[0][1], Qf[cs][1], d0);
            d1 = MFMA16(Kf[1][0], Qf[cs][0], d1);
            d1 = MFMA16(Kf[1][1], Qf[cs][1], d1);
            f32x4 p0, p1;
            #pragma unroll
            for (int r = 0; r < 4; ++r) { p0[r] = __expf(d0[r]); p1[r] = __expf(d1[r]); }
            lsum[cs] += (p0[0] + p0[1] + p0[2] + p0[3]) +
                        (p1[0] + p1[1] + p1[2] + p1[3]);
            bf16x8 pf;
            #pragma unroll
            for (int r = 0; r < 4; ++r) { pf[r] = bfb(p0[r]); pf[4 + r] = bfb(p1[r]); }
            Pf[cs] = pf;
        }

        #pragma unroll
        for (int cs = 0; cs < 4; ++cs)
            #pragma unroll
            for (int fs = 0; fs < 4; ++fs)
                acc[cs][fs] = MFMA16(Pf[cs], Vf[fs], acc[cs][fs]);

        __syncthreads();
    }

    // ---- softmax denominators
    #pragma unroll
    for (int cs = 0; cs < 4; ++cs) {
        lsum[cs] += __shfl_xor(lsum[cs], 16);
        lsum[cs] += __shfl_xor(lsum[cs], 32);
        if (g == 0) ls_lds[wave][cs * 16 + lr] = lsum[cs];
    }
    __syncthreads();

    // ---- fused Wf epilogue
    #pragma unroll
    for (int cs = 0; cs < 4; ++cs) {
        f32x4 linv;
        #pragma unroll
        for (int r = 0; r < 4; ++r)
            linv[r] = 1.f / ls_lds[wave][cs * 16 + 4 * g + r];
        #pragma unroll
        for (int r = 0; r < 4; ++r) {
            const int cc = c0 + cs * 16 + 4 * g + r;
            const int c  = (cc < C_) ? cc : (C_ - 1);
            const float* wrow = Wf + (size_t)c * (4 * F_) + br * F_ + lr;
            float p = 0.f;
            #pragma unroll
            for (int fs = 0; fs < 4; ++fs)
                p += acc[cs][fs][r] * wrow[fs * 16];
            p *= linv[r];
            p += __shfl_xor(p, 1);
            p += __shfl_xor(p, 2);
            p += __shfl_xor(p, 4);
            p += __shfl_xor(p, 8);
            if (lr == 0 && cc < C_)
                atomicAdd(&yhat[(size_t)b * C_ + cc], p);
        }
    }
}

// ---------------------------------------------------------------------------
// Kernel 3: BCE from accumulated yhat (+bf), write y_hat out, partial sums
// ---------------------------------------------------------------------------
__global__ __launch_bounds__(256) void bce_kernel(
    const float* __restrict__ yhat, const float* __restrict__ bf,
    const float* __restrict__ y, float* __restrict__ out,
    float* __restrict__ partials)
{
    const int p = blockIdx.x * 256 + threadIdx.x;
    float bce = 0.f;
    if (p < B_ * C_) {
        const int c = p % C_;
        const float yh = yhat[p] + bf[c];
        out[p] = yh;
        bce = fmaxf(yh, 0.f) - yh * y[p] + log1pf(expf(-fabsf(yh)));
    }
    __shared__ float red[256];
    red[threadIdx.x] = bce;
    __syncthreads();
    #pragma unroll
    for (int stp = 128; stp > 0; stp >>= 1) {
        if (threadIdx.x < stp) red[threadIdx.x] += red[threadIdx.x + stp];
        __syncthreads();
    }
    if (threadIdx.x == 0) partials[blockIdx.x] = red[0];
}

__global__ __launch_bounds__(256) void loss_kernel(
    const float* __restrict__ partials, int n, float* __restrict__ out_loss)
{
    __shared__ float red[256];
    float v = (threadIdx.x < n) ? partials[threadIdx.x] : 0.f;
    red[threadIdx.x] = v;
    __syncthreads();
    #pragma unroll
    for (int stp = 128; stp > 0; stp >>= 1) {
        if (threadIdx.x < stp) red[threadIdx.x] += red[threadIdx.x + stp];
        __syncthreads();
    }
    if (threadIdx.x == 0) *out_loss = red[0] / (float)(B_ * C_);
}

// ---------------------------------------------------------------------------
extern "C" void kernel_launch(void* const* d_in, const int* in_sizes, int n_in,
                              void* d_out, int out_size, void* d_ws, size_t ws_size,
                              hipStream_t stream)
{
    const int*   x     = (const int*)  d_in[0];
    const float* y     = (const float*)d_in[1];
    const float* embed = (const float*)d_in[2];
    const float* w3    = (const float*)d_in[3];
    const float* b3    = (const float*)d_in[4];
    const float* w5    = (const float*)d_in[5];
    const float* b5    = (const float*)d_in[6];
    const float* w7    = (const float*)d_in[7];
    const float* b7    = (const float*)d_in[8];
    const float* w9    = (const float*)d_in[9];
    const float* b9    = (const float*)d_in[10];
    const float* U3    = (const float*)d_in[11];
    const float* U5    = (const float*)d_in[12];
    const float* U7    = (const float*)d_in[13];
    const float* U9    = (const float*)d_in[14];
    const float* Wf    = (const float*)d_in[15];
    const float* bfv   = (const float*)d_in[16];

    char* wsb = (char*)d_ws;
    float*          yhat     = (float*)wsb;                    // 35688 f
    float*          partials = (float*)(wsb + 142848);         // 140 f
    unsigned short* Wp       = (unsigned short*)(wsb + 143616);// 294912 bf16
    char*           hkB      = wsb + 737280;                   // 4 MB
    char*           hvB      = wsb + 737280 + 4194304;         // 4 MB
    float*          out      = (float*)d_out;

    prep_kernel<<<1152, 256, 0, stream>>>(w3, w5, w7, w9, Wp, yhat);

    conv_mfma_kernel<<<256, 256, 0, stream>>>(
        x, embed, Wp, b3, b5, b7, b9, hkB, hvB);

    dim3 ag((C_ + 255) / 256, B_, 4);   // 35 x 4 x 4
    attn_mfma_kernel<<<ag, 256, 0, stream>>>(U3, U5, U7, U9, hkB, hvB, Wf, yhat);

    const int nblk = (B_ * C_ + 255) / 256;   // 140
    bce_kernel<<<nblk, 256, 0, stream>>>(yhat, bfv, y, out, partials);
    loss_kernel<<<1, 256, 0, stream>>>(partials, nblk, out + B_ * C_);
}

// Round 6
// 235.734 us; speedup vs baseline: 19.6611x; 1.0927x over previous
//
#include <hip/hip_runtime.h>
#include <hip/hip_bf16.h>

#define B_ 4
#define S_ 2048
#define E_ 100
#define F_ 64
#define C_ 8922
#define V_ 52000

typedef short bf16x8 __attribute__((ext_vector_type(8)));
typedef short s16x4  __attribute__((ext_vector_type(4)));
typedef float f32x4  __attribute__((ext_vector_type(4)));

#define MFMA16(A, B, C) __builtin_amdgcn_mfma_f32_16x16x32_bf16(A, B, C, 0, 0, 0)
#define LOG2E 1.44269504088896f
#define EXP2F(x) __builtin_amdgcn_exp2f(x)

__device__ inline short bfb(float x) {
    __hip_bfloat16 h = __float2bfloat16(x);
    return *reinterpret_cast<short*>(&h);
}

// ---------------------------------------------------------------------------
// Kernel 0: weight prepack (per-lane MFMA B-fragments, conv k-map
// k = g*4 + (j&3) + ((j>>2)<<4)) + zero yhat.  (unchanged from R4)
// ---------------------------------------------------------------------------
__global__ __launch_bounds__(256) void prep_kernel(
    const float* __restrict__ w3, const float* __restrict__ w5,
    const float* __restrict__ w7, const float* __restrict__ w9,
    unsigned short* __restrict__ Wp, float* __restrict__ yhat)
{
    const int gid = blockIdx.x * 256 + threadIdx.x;   // 0..294911
    if (gid < B_ * C_) yhat[gid] = 0.f;

    const int j    = gid & 7;
    const int lane = (gid >> 3) & 63;
    const int nt   = (gid >> 9) & 15;
    const int step = gid >> 13;          // 0..35
    const int d    = step >> 2;
    const int ec   = step & 3;
    const int g    = lane >> 4;
    const int lr   = lane & 15;
    const int k    = g * 4 + (j & 3) + ((j >> 2) << 4);
    const int e    = ec * 32 + k;
    const int n    = nt * 16 + lr;
    const int br   = n >> 6;
    const int f    = n & 63;
    const int kb   = 3 + 2 * br;
    const int dp   = d - (3 - br);

    float val = 0.f;
    if (e < E_ && dp >= 0 && dp < kb) {
        const float* w = (br == 0) ? w3 : (br == 1) ? w5 : (br == 2) ? w7 : w9;
        val = w[((size_t)f * E_ + e) * kb + dp];
    }
    Wp[gid] = (unsigned short)bfb(val);
}

// ---------------------------------------------------------------------------
// h bf16 global layouts (byte-identical to R3/R4 validated layouts):
//  hk per (br,b): s*128 + (f*2 ^ ((s&7)<<4))
//  hv per (br,b): (s>>5)*4096 + (f>>4)*1024 + ((s>>4)&1)*512
//                 + ((s>>2)&3)*128 + (s&3)*32 + (f&15)*2
// ---------------------------------------------------------------------------

// ---------------------------------------------------------------------------
// Kernel 1: conv as MFMA GEMM (A/B frag math unchanged from R4).
// NEW epilogue: per-wave LDS bounce -> 16B vectorized stores to hk/hv.
// ---------------------------------------------------------------------------
__global__ __launch_bounds__(256, 1) void conv_mfma_kernel(
    const int* __restrict__ x, const float* __restrict__ embed,
    const unsigned short* __restrict__ Wp,
    const float* __restrict__ b3, const float* __restrict__ b5,
    const float* __restrict__ b7, const float* __restrict__ b9,
    char* __restrict__ hkB, char* __restrict__ hvB)
{
    __shared__ unsigned short xeT[40 * 128];   // 10 KB swizzled bf16 tile
    __shared__ float ep[4][32][68];            // 34 KB epilogue bounce

    const int blk  = blockIdx.x;
    const int b    = blk >> 6;
    const int st   = blk & 63;
    const int s0   = st * 32;
    const int tid  = threadIdx.x;
    const int wave = tid >> 6;
    const int lane = tid & 63;
    const int g    = lane >> 4;
    const int lr   = lane & 15;

    // ---- stage xe: 40 rows x 128 e (bf16, row-XOR swizzled)
    for (int task = tid; task < 640; task += 256) {
        const int row = task >> 4;
        const int o   = task & 15;
        const int s   = s0 - 4 + row;
        float v[8];
        #pragma unroll
        for (int i = 0; i < 8; ++i) v[i] = 0.f;
        if (s >= 0 && s < S_ && o < 13) {
            const int tok = x[b * S_ + s];
            const float* er = embed + (size_t)tok * E_ + o * 8;
            if (o < 12) {
                #pragma unroll
                for (int i = 0; i < 8; ++i) v[i] = er[i];
            } else {
                v[0] = er[0]; v[1] = er[1]; v[2] = er[2]; v[3] = er[3];
            }
        }
        unsigned short u[8];
        #pragma unroll
        for (int i = 0; i < 8; ++i) u[i] = (unsigned short)bfb(v[i]);
        const unsigned xr = ((unsigned)(row & 15)) << 3;
        char* base = (char*)xeT + row * 256;
        *(uint2*)(base + (((unsigned)(o * 16)) ^ xr))     = *(const uint2*)&u[0];
        *(uint2*)(base + (((unsigned)(o * 16 + 8)) ^ xr)) = *(const uint2*)&u[4];
    }
    __syncthreads();

    f32x4 acc[2][4];
    #pragma unroll
    for (int m2 = 0; m2 < 2; ++m2)
        #pragma unroll
        for (int ns = 0; ns < 4; ++ns)
            acc[m2][ns] = (f32x4){0.f, 0.f, 0.f, 0.f};

    const char* xb = (const char*)xeT;
    #pragma unroll
    for (int step = 0; step < 36; ++step) {
        const int d  = step >> 2;
        const int ec = step & 3;

        bf16x8 Af[2];
        #pragma unroll
        for (int m2 = 0; m2 < 2; ++m2) {
            const int row = m2 * 16 + lr + d;
            const unsigned xr = ((unsigned)(row & 15)) << 3;
            const unsigned rb = (unsigned)row * 256;
            const unsigned e0 = (unsigned)(ec * 64 + g * 8);
            const s16x4 lo = *(const s16x4*)(xb + rb + (e0 ^ xr));
            const s16x4 hi = *(const s16x4*)(xb + rb + ((e0 + 32) ^ xr));
            Af[m2] = __builtin_shufflevector(lo, hi, 0, 1, 2, 3, 4, 5, 6, 7);
        }

        bf16x8 Bf[4];
        #pragma unroll
        for (int ns = 0; ns < 4; ++ns)
            Bf[ns] = *(const bf16x8*)(Wp +
                     (((size_t)step * 16 + wave * 4 + ns) * 64 + lane) * 8);

        #pragma unroll
        for (int m2 = 0; m2 < 2; ++m2)
            #pragma unroll
            for (int ns = 0; ns < 4; ++ns)
                acc[m2][ns] = MFMA16(Af[m2], Bf[ns], acc[m2][ns]);
    }

    // ---- epilogue: bias+tanh -> LDS -> vectorized 16B stores to hk & hv
    const float* bias = (wave == 0) ? b3 : (wave == 1) ? b5 : (wave == 2) ? b7 : b9;
    float bia[4];
    #pragma unroll
    for (int ns = 0; ns < 4; ++ns) bia[ns] = bias[ns * 16 + lr];

    #pragma unroll
    for (int m2 = 0; m2 < 2; ++m2)
        #pragma unroll
        for (int ns = 0; ns < 4; ++ns)
            #pragma unroll
            for (int r = 0; r < 4; ++r)
                ep[wave][m2 * 16 + 4 * g + r][ns * 16 + lr] =
                    tanhf(acc[m2][ns][r] + bia[ns]);
    __syncthreads();

    const size_t hbase = (size_t)(wave * 4 + b) * 262144;   // per (br,b) 256 KB
    #pragma unroll
    for (int it = 0; it < 4; ++it) {
        const int task = it * 64 + lane;
        const int sl = task >> 3;        // 0..31
        const int o  = task & 7;         // f-octet
        const int s  = s0 + sl;
        float v[8];
        *(float4*)&v[0] = *(const float4*)&ep[wave][sl][o * 8];
        *(float4*)&v[4] = *(const float4*)&ep[wave][sl][o * 8 + 4];
        unsigned short u[8];
        #pragma unroll
        for (int i = 0; i < 8; ++i) u[i] = (unsigned short)bfb(v[i]);
        uint4 pk;
        pk.x = (unsigned)u[0] | ((unsigned)u[1] << 16);
        pk.y = (unsigned)u[2] | ((unsigned)u[3] << 16);
        pk.z = (unsigned)u[4] | ((unsigned)u[5] << 16);
        pk.w = (unsigned)u[6] | ((unsigned)u[7] << 16);
        char* hka = hkB + hbase + (size_t)s * 128 +
                    (((unsigned)(o * 16)) ^ (((unsigned)(s & 7)) << 4));
        *(uint4*)hka = pk;
        char* hva = hvB + hbase + (size_t)(s >> 5) * 4096 + (o >> 1) * 1024 +
                    ((s >> 4) & 1) * 512 + ((s >> 2) & 3) * 128 +
                    (s & 3) * 32 + (o & 1) * 16;
        *(uint4*)hva = pk;
    }
}

// ---------------------------------------------------------------------------
// Kernel 2: bf16 MFMA flash attention, KVBLK=64, XCD-pinned linear grid,
// b128 K-frags (QKT k-map phi(g,j)=g*8+j on BOTH A and B), exp2-prescaled Q,
// fused Wf epilogue (atomicAdd into yhat).
// ---------------------------------------------------------------------------
#define TRREAD(dst, off) \
    asm volatile("ds_read_b64_tr_b16 %0, %1 offset:" #off \
                 : "=v"(dst) : "v"(vaddr));

typedef const __attribute__((address_space(1))) unsigned int* as1_u32p;
typedef __attribute__((address_space(3))) unsigned int* as3_u32p;

__device__ inline void gl_lds16(const void* g, unsigned lds_off) {
    __builtin_amdgcn_global_load_lds((as1_u32p)(uintptr_t)g,
                                     (as3_u32p)(uintptr_t)lds_off, 16, 0, 0);
}

__global__ __launch_bounds__(256, 2) void attn_mfma_kernel(
    const float* __restrict__ U3, const float* __restrict__ U5,
    const float* __restrict__ U7, const float* __restrict__ U9,
    const char* __restrict__ hkG, const char* __restrict__ hvG,
    const float* __restrict__ Wf, float* __restrict__ yhat)
{
    __shared__ unsigned short Kbuf[2][4096];   // 2 x 8KB (64s x 64f, XOR-swz)
    __shared__ unsigned short Vbuf[2][4096];   // 2 x 8KB (tr-subtiled, 2 halves)
    __shared__ float ls_lds[4][64];

    const int tid  = threadIdx.x;
    const int wave = tid >> 6;
    const int lane = tid & 63;
    const int g    = lane >> 4;
    const int lr   = lane & 15;

    // XCD-pinned decode: all 35 c-tiles of one (br,b) land on one XCD (bid%8)
    const int bid = blockIdx.x;
    const int t2  = bid >> 3;                  // 0..69
    const int grp = (bid & 7) + 8 * (t2 / 35); // 0..15
    const int ct  = t2 % 35;                   // c-tile
    const int br  = grp >> 2;
    const int b   = grp & 3;
    const int c0  = ct * 256 + wave * 64;

    const float* __restrict__ U =
        (br == 0) ? U3 : (br == 1) ? U5 : (br == 2) ? U7 : U9;

    // ---- Q fragments, phi(g,j) = g*8+j, pre-scaled by log2(e)
    bf16x8 Qf[4][2];
    #pragma unroll
    for (int cs = 0; cs < 4; ++cs) {
        int c = c0 + cs * 16 + lr;
        if (c > C_ - 1) c = C_ - 1;
        const float* Uc = U + (size_t)c * F_;
        #pragma unroll
        for (int kh = 0; kh < 2; ++kh) {
            const float4 lo = *(const float4*)(Uc + kh * 32 + g * 8);
            const float4 hi = *(const float4*)(Uc + kh * 32 + g * 8 + 4);
            bf16x8 q;
            q[0] = bfb(lo.x * LOG2E); q[1] = bfb(lo.y * LOG2E);
            q[2] = bfb(lo.z * LOG2E); q[3] = bfb(lo.w * LOG2E);
            q[4] = bfb(hi.x * LOG2E); q[5] = bfb(hi.y * LOG2E);
            q[6] = bfb(hi.z * LOG2E); q[7] = bfb(hi.w * LOG2E);
            Qf[cs][kh] = q;
        }
    }

    f32x4 acc[4][4];
    #pragma unroll
    for (int cs = 0; cs < 4; ++cs)
        #pragma unroll
        for (int fs = 0; fs < 4; ++fs)
            acc[cs][fs] = (f32x4){0.f, 0.f, 0.f, 0.f};
    float lsum[4] = {0.f, 0.f, 0.f, 0.f};

    const char* hkB = hkG + (size_t)grp * 262144;
    const char* hvB = hvG + (size_t)grp * 262144;
    const unsigned kL0 = (unsigned)(uintptr_t)&Kbuf[0][0];
    const unsigned vL0 = (unsigned)(uintptr_t)&Vbuf[0][0];

    // stage one 64-s chunk (8KB K + 8KB V): 4 issues/thread
#define STAGEKV(chunk, buf) {                                              \
        const size_t go = (size_t)(chunk) * 8192 + wave * 2048 +           \
                          (size_t)(lane << 4);                             \
        const unsigned lo = (unsigned)((buf) * 8192 + wave * 2048);        \
        gl_lds16(hkB + go,        kL0 + lo);                               \
        gl_lds16(hkB + go + 1024, kL0 + lo + 1024);                        \
        gl_lds16(hvB + go,        vL0 + lo);                               \
        gl_lds16(hvB + go + 1024, vL0 + lo + 1024); }

    STAGEKV(0, 0)
    __syncthreads();

    const unsigned ksw = ((unsigned)(lr & 7)) << 4;

    for (int t = 0; t < 32; ++t) {
        const int cur = t & 1;
        if (t < 31) STAGEKV(t + 1, cur ^ 1)

        // ---- K fragments: one ds_read_b128 each (phi(g,j)=g*8+j)
        const char* Kb = (const char*)Kbuf + cur * 8192;
        bf16x8 Kf[4][2];
        #pragma unroll
        for (int sh = 0; sh < 4; ++sh) {
            const unsigned rowb = (unsigned)((16 * sh + lr) * 128);
            #pragma unroll
            for (int kh = 0; kh < 2; ++kh)
                Kf[sh][kh] = *(const bf16x8*)(
                    Kb + rowb + (((unsigned)(kh * 64 + g * 16)) ^ ksw));
        }

        // ---- QK^T -> exp2 -> P fragments (P: s-rows per lane fixed by C/D)
        bf16x8 Pf[4][2];
        #pragma unroll
        for (int cs = 0; cs < 4; ++cs) {
            f32x4 d0 = (f32x4){0.f,0.f,0.f,0.f}, d1 = d0, d2 = d0, d3 = d0;
            d0 = MFMA16(Kf[0][0], Qf[cs][0], d0);
            d0 = MFMA16(Kf[0][1], Qf[cs][1], d0);
            d1 = MFMA16(Kf[1][0], Qf[cs][0], d1);
            d1 = MFMA16(Kf[1][1], Qf[cs][1], d1);
            d2 = MFMA16(Kf[2][0], Qf[cs][0], d2);
            d2 = MFMA16(Kf[2][1], Qf[cs][1], d2);
            d3 = MFMA16(Kf[3][0], Qf[cs][0], d3);
            d3 = MFMA16(Kf[3][1], Qf[cs][1], d3);
            float p[16];
            #pragma unroll
            for (int r = 0; r < 4; ++r) {
                p[r]      = EXP2F(d0[r]);
                p[4 + r]  = EXP2F(d1[r]);
                p[8 + r]  = EXP2F(d2[r]);
                p[12 + r] = EXP2F(d3[r]);
            }
            float sm = 0.f;
            #pragma unroll
            for (int r = 0; r < 16; ++r) sm += p[r];
            lsum[cs] += sm;
            bf16x8 pf0, pf1;
            #pragma unroll
            for (int r = 0; r < 8; ++r) { pf0[r] = bfb(p[r]); pf1[r] = bfb(p[8 + r]); }
            Pf[cs][0] = pf0;
            Pf[cs][1] = pf1;
        }

        // ---- PV: stream V per fs via hardware transpose-read
        const unsigned vaddr = vL0 + (unsigned)(cur * 8192 + g * 128 + lr * 2);
#define PVBLK(fs, O0, O1, O2, O3)                                          \
        {                                                                  \
            s16x4 a0, a1, b0, b1;                                          \
            TRREAD(a0, O0) TRREAD(a1, O1) TRREAD(b0, O2) TRREAD(b1, O3)    \
            asm volatile("s_waitcnt lgkmcnt(0)" ::: "memory");             \
            __builtin_amdgcn_sched_barrier(0);                             \
            const bf16x8 V0 = __builtin_shufflevector(a0, a1, 0,1,2,3,4,5,6,7); \
            const bf16x8 V1 = __builtin_shufflevector(b0, b1, 0,1,2,3,4,5,6,7); \
            _Pragma("unroll")                                              \
            for (int cs = 0; cs < 4; ++cs) {                               \
                acc[cs][fs] = MFMA16(Pf[cs][0], V0, acc[cs][fs]);          \
                acc[cs][fs] = MFMA16(Pf[cs][1], V1, acc[cs][fs]);          \
            }                                                              \
        }
        PVBLK(0,    0,  512, 4096, 4608)
        PVBLK(1, 1024, 1536, 5120, 5632)
        PVBLK(2, 2048, 2560, 6144, 6656)
        PVBLK(3, 3072, 3584, 7168, 7680)

        __syncthreads();
    }

    // ---- softmax denominators (sum over the 4 g-groups' s-rows)
    #pragma unroll
    for (int cs = 0; cs < 4; ++cs) {
        lsum[cs] += __shfl_xor(lsum[cs], 16);
        lsum[cs] += __shfl_xor(lsum[cs], 32);
        if (g == 0) ls_lds[wave][cs * 16 + lr] = lsum[cs];
    }
    __syncthreads();

    // ---- fused Wf epilogue: per-c dot over f, 16-lane reduce, atomicAdd
    #pragma unroll
    for (int cs = 0; cs < 4; ++cs) {
        f32x4 linv;
        #pragma unroll
        for (int r = 0; r < 4; ++r)
            linv[r] = 1.f / ls_lds[wave][cs * 16 + 4 * g + r];
        #pragma unroll
        for (int r = 0; r < 4; ++r) {
            const int cc = c0 + cs * 16 + 4 * g + r;
            const int c  = (cc < C_) ? cc : (C_ - 1);
            const float* wrow = Wf + (size_t)c * (4 * F_) + br * F_ + lr;
            float p = 0.f;
            #pragma unroll
            for (int fs = 0; fs < 4; ++fs)
                p += acc[cs][fs][r] * wrow[fs * 16];
            p *= linv[r];
            p += __shfl_xor(p, 1);
            p += __shfl_xor(p, 2);
            p += __shfl_xor(p, 4);
            p += __shfl_xor(p, 8);
            if (lr == 0 && cc < C_)
                atomicAdd(&yhat[(size_t)b * C_ + cc], p);
        }
    }
}

// ---------------------------------------------------------------------------
// Kernel 3: BCE from accumulated yhat (+bf), write y_hat out, partial sums
// ---------------------------------------------------------------------------
__global__ __launch_bounds__(256) void bce_kernel(
    const float* __restrict__ yhat, const float* __restrict__ bf,
    const float* __restrict__ y, float* __restrict__ out,
    float* __restrict__ partials)
{
    const int p = blockIdx.x * 256 + threadIdx.x;
    float bce = 0.f;
    if (p < B_ * C_) {
        const int c = p % C_;
        const float yh = yhat[p] + bf[c];
        out[p] = yh;
        bce = fmaxf(yh, 0.f) - yh * y[p] + log1pf(expf(-fabsf(yh)));
    }
    __shared__ float red[256];
    red[threadIdx.x] = bce;
    __syncthreads();
    #pragma unroll
    for (int stp = 128; stp > 0; stp >>= 1) {
        if (threadIdx.x < stp) red[threadIdx.x] += red[threadIdx.x + stp];
        __syncthreads();
    }
    if (threadIdx.x == 0) partials[blockIdx.x] = red[0];
}

__global__ __launch_bounds__(256) void loss_kernel(
    const float* __restrict__ partials, int n, float* __restrict__ out_loss)
{
    __shared__ float red[256];
    float v = (threadIdx.x < n) ? partials[threadIdx.x] : 0.f;
    red[threadIdx.x] = v;
    __syncthreads();
    #pragma unroll
    for (int stp = 128; stp > 0; stp >>= 1) {
        if (threadIdx.x < stp) red[threadIdx.x] += red[threadIdx.x + stp];
        __syncthreads();
    }
    if (threadIdx.x == 0) *out_loss = red[0] / (float)(B_ * C_);
}

// ---------------------------------------------------------------------------
extern "C" void kernel_launch(void* const* d_in, const int* in_sizes, int n_in,
                              void* d_out, int out_size, void* d_ws, size_t ws_size,
                              hipStream_t stream)
{
    const int*   x     = (const int*)  d_in[0];
    const float* y     = (const float*)d_in[1];
    const float* embed = (const float*)d_in[2];
    const float* w3    = (const float*)d_in[3];
    const float* b3    = (const float*)d_in[4];
    const float* w5    = (const float*)d_in[5];
    const float* b5    = (const float*)d_in[6];
    const float* w7    = (const float*)d_in[7];
    const float* b7    = (const float*)d_in[8];
    const float* w9    = (const float*)d_in[9];
    const float* b9    = (const float*)d_in[10];
    const float* U3    = (const float*)d_in[11];
    const float* U5    = (const float*)d_in[12];
    const float* U7    = (const float*)d_in[13];
    const float* U9    = (const float*)d_in[14];
    const float* Wf    = (const float*)d_in[15];
    const float* bfv   = (const float*)d_in[16];

    char* wsb = (char*)d_ws;
    float*          yhat     = (float*)wsb;                    // 35688 f
    float*          partials = (float*)(wsb + 142848);         // 140 f
    unsigned short* Wp       = (unsigned short*)(wsb + 143616);// 294912 bf16
    char*           hkB      = wsb + 737280;                   // 4 MB
    char*           hvB      = wsb + 737280 + 4194304;         // 4 MB
    float*          out      = (float*)d_out;

    prep_kernel<<<1152, 256, 0, stream>>>(w3, w5, w7, w9, Wp, yhat);

    conv_mfma_kernel<<<256, 256, 0, stream>>>(
        x, embed, Wp, b3, b5, b7, b9, hkB, hvB);

    attn_mfma_kernel<<<560, 256, 0, stream>>>(U3, U5, U7, U9, hkB, hvB, Wf, yhat);

    const int nblk = (B_ * C_ + 255) / 256;   // 140
    bce_kernel<<<nblk, 256, 0, stream>>>(yhat, bfv, y, out, partials);
    loss_kernel<<<1, 256, 0, stream>>>(partials, nblk, out + B_ * C_);
}

// Round 7
// 225.935 us; speedup vs baseline: 20.5137x; 1.0434x over previous
//
#include <hip/hip_runtime.h>
#include <hip/hip_bf16.h>

#define B_ 4
#define S_ 2048
#define E_ 100
#define F_ 64
#define C_ 8922
#define V_ 52000

typedef short bf16x8 __attribute__((ext_vector_type(8)));
typedef short s16x4  __attribute__((ext_vector_type(4)));
typedef float f32x4  __attribute__((ext_vector_type(4)));

#define MFMA16(A, B, C) __builtin_amdgcn_mfma_f32_16x16x32_bf16(A, B, C, 0, 0, 0)
#define LOG2E 1.44269504088896f
#define EXP2F(x) __builtin_amdgcn_exp2f(x)

__device__ inline short bfb(float x) {
    __hip_bfloat16 h = __float2bfloat16(x);
    return *reinterpret_cast<short*>(&h);
}

// ---------------------------------------------------------------------------
// Kernel 0: weight prepack (per-lane MFMA B-fragments, conv k-map
// k = g*4 + (j&3) + ((j>>2)<<4)) + zero num/den accumulators.
// ---------------------------------------------------------------------------
__global__ __launch_bounds__(256) void prep_kernel(
    const float* __restrict__ w3, const float* __restrict__ w5,
    const float* __restrict__ w7, const float* __restrict__ w9,
    unsigned short* __restrict__ Wp,
    float* __restrict__ num, float* __restrict__ den)
{
    const int gid = blockIdx.x * 256 + threadIdx.x;   // 0..294911
    if (gid < 4 * B_ * C_) { num[gid] = 0.f; den[gid] = 0.f; }

    const int j    = gid & 7;
    const int lane = (gid >> 3) & 63;
    const int nt   = (gid >> 9) & 15;
    const int step = gid >> 13;          // 0..35
    const int d    = step >> 2;
    const int ec   = step & 3;
    const int g    = lane >> 4;
    const int lr   = lane & 15;
    const int k    = g * 4 + (j & 3) + ((j >> 2) << 4);
    const int e    = ec * 32 + k;
    const int n    = nt * 16 + lr;
    const int br   = n >> 6;
    const int f    = n & 63;
    const int kb   = 3 + 2 * br;
    const int dp   = d - (3 - br);

    float val = 0.f;
    if (e < E_ && dp >= 0 && dp < kb) {
        const float* w = (br == 0) ? w3 : (br == 1) ? w5 : (br == 2) ? w7 : w9;
        val = w[((size_t)f * E_ + e) * kb + dp];
    }
    Wp[gid] = (unsigned short)bfb(val);
}

// ---------------------------------------------------------------------------
// h bf16 global layouts (byte-identical to R3..R6 validated layouts):
//  hk per (br,b): s*128 + (f*2 ^ ((s&7)<<4))
//  hv per (br,b): (s>>5)*4096 + (f>>4)*1024 + ((s>>4)&1)*512
//                 + ((s>>2)&3)*128 + (s&3)*32 + (f&15)*2
// ---------------------------------------------------------------------------

// ---------------------------------------------------------------------------
// Kernel 1: conv as MFMA GEMM, 16-s tiles (512 blocks -> 2 blocks/CU).
// Wave w = branch w: computes [16 s] x [64 f]. K-loop 36 steps.
// ---------------------------------------------------------------------------
__global__ __launch_bounds__(256, 2) void conv_mfma_kernel(
    const int* __restrict__ x, const float* __restrict__ embed,
    const unsigned short* __restrict__ Wp,
    const float* __restrict__ b3, const float* __restrict__ b5,
    const float* __restrict__ b7, const float* __restrict__ b9,
    char* __restrict__ hkB, char* __restrict__ hvB)
{
    __shared__ unsigned short xeT[24 * 128];   // 6 KB swizzled bf16 tile
    __shared__ float ep[4][16][68];            // 17 KB epilogue bounce

    const int blk  = blockIdx.x;
    const int b    = blk >> 7;
    const int st   = blk & 127;
    const int s0   = st * 16;
    const int tid  = threadIdx.x;
    const int wave = tid >> 6;
    const int lane = tid & 63;
    const int g    = lane >> 4;
    const int lr   = lane & 15;

    // ---- stage xe: 24 rows x 128 e (bf16, row-XOR swizzled)
    for (int task = tid; task < 384; task += 256) {
        const int row = task >> 4;
        const int o   = task & 15;
        const int s   = s0 - 4 + row;
        float v[8];
        #pragma unroll
        for (int i = 0; i < 8; ++i) v[i] = 0.f;
        if (s >= 0 && s < S_ && o < 13) {
            const int tok = x[b * S_ + s];
            const float* er = embed + (size_t)tok * E_ + o * 8;
            if (o < 12) {
                #pragma unroll
                for (int i = 0; i < 8; ++i) v[i] = er[i];
            } else {
                v[0] = er[0]; v[1] = er[1]; v[2] = er[2]; v[3] = er[3];
            }
        }
        unsigned short u[8];
        #pragma unroll
        for (int i = 0; i < 8; ++i) u[i] = (unsigned short)bfb(v[i]);
        const unsigned xr = ((unsigned)(row & 15)) << 3;
        char* base = (char*)xeT + row * 256;
        *(uint2*)(base + (((unsigned)(o * 16)) ^ xr))     = *(const uint2*)&u[0];
        *(uint2*)(base + (((unsigned)(o * 16 + 8)) ^ xr)) = *(const uint2*)&u[4];
    }
    __syncthreads();

    f32x4 acc[4];
    #pragma unroll
    for (int ns = 0; ns < 4; ++ns) acc[ns] = (f32x4){0.f, 0.f, 0.f, 0.f};

    const char* xb = (const char*)xeT;
    #pragma unroll
    for (int step = 0; step < 36; ++step) {
        const int d  = step >> 2;
        const int ec = step & 3;

        bf16x8 Af;
        {
            const int row = lr + d;
            const unsigned xr = ((unsigned)(row & 15)) << 3;
            const unsigned rb = (unsigned)row * 256;
            const unsigned e0 = (unsigned)(ec * 64 + g * 8);
            const s16x4 lo = *(const s16x4*)(xb + rb + (e0 ^ xr));
            const s16x4 hi = *(const s16x4*)(xb + rb + ((e0 + 32) ^ xr));
            Af = __builtin_shufflevector(lo, hi, 0, 1, 2, 3, 4, 5, 6, 7);
        }

        bf16x8 Bf[4];
        #pragma unroll
        for (int ns = 0; ns < 4; ++ns)
            Bf[ns] = *(const bf16x8*)(Wp +
                     (((size_t)step * 16 + wave * 4 + ns) * 64 + lane) * 8);

        #pragma unroll
        for (int ns = 0; ns < 4; ++ns)
            acc[ns] = MFMA16(Af, Bf[ns], acc[ns]);
    }

    // ---- epilogue: bias+tanh -> LDS -> vectorized 16B stores to hk & hv
    const float* bias = (wave == 0) ? b3 : (wave == 1) ? b5 : (wave == 2) ? b7 : b9;
    float bia[4];
    #pragma unroll
    for (int ns = 0; ns < 4; ++ns) bia[ns] = bias[ns * 16 + lr];

    #pragma unroll
    for (int ns = 0; ns < 4; ++ns)
        #pragma unroll
        for (int r = 0; r < 4; ++r)
            ep[wave][4 * g + r][ns * 16 + lr] = tanhf(acc[ns][r] + bia[ns]);
    __syncthreads();

    const size_t hbase = (size_t)(wave * 4 + b) * 262144;   // per (br,b) 256 KB
    #pragma unroll
    for (int it = 0; it < 2; ++it) {
        const int task = it * 64 + lane;
        const int sl = task >> 3;        // 0..15
        const int o  = task & 7;         // f-octet
        const int s  = s0 + sl;
        float v[8];
        *(float4*)&v[0] = *(const float4*)&ep[wave][sl][o * 8];
        *(float4*)&v[4] = *(const float4*)&ep[wave][sl][o * 8 + 4];
        unsigned short u[8];
        #pragma unroll
        for (int i = 0; i < 8; ++i) u[i] = (unsigned short)bfb(v[i]);
        uint4 pk;
        pk.x = (unsigned)u[0] | ((unsigned)u[1] << 16);
        pk.y = (unsigned)u[2] | ((unsigned)u[3] << 16);
        pk.z = (unsigned)u[4] | ((unsigned)u[5] << 16);
        pk.w = (unsigned)u[6] | ((unsigned)u[7] << 16);
        char* hka = hkB + hbase + (size_t)s * 128 +
                    (((unsigned)(o * 16)) ^ (((unsigned)(s & 7)) << 4));
        *(uint4*)hka = pk;
        char* hva = hvB + hbase + (size_t)(s >> 5) * 4096 + (o >> 1) * 1024 +
                    ((s >> 4) & 1) * 512 + ((s >> 2) & 3) * 128 +
                    (s & 3) * 32 + (o & 1) * 16;
        *(uint4*)hva = pk;
    }
}

// ---------------------------------------------------------------------------
// Kernel 2: bf16 MFMA flash attention, KVBLK=64, S-split x2, XCD-pinned grid,
// setprio around MFMA clusters, fused unnormalized-Wf epilogue into num/den.
// ---------------------------------------------------------------------------
#define TRREAD(dst, off) \
    asm volatile("ds_read_b64_tr_b16 %0, %1 offset:" #off \
                 : "=v"(dst) : "v"(vaddr));

typedef const __attribute__((address_space(1))) unsigned int* as1_u32p;
typedef __attribute__((address_space(3))) unsigned int* as3_u32p;

__device__ inline void gl_lds16(const void* g, unsigned lds_off) {
    __builtin_amdgcn_global_load_lds((as1_u32p)(uintptr_t)g,
                                     (as3_u32p)(uintptr_t)lds_off, 16, 0, 0);
}

__global__ __launch_bounds__(256, 2) void attn_mfma_kernel(
    const float* __restrict__ U3, const float* __restrict__ U5,
    const float* __restrict__ U7, const float* __restrict__ U9,
    const char* __restrict__ hkG, const char* __restrict__ hvG,
    const float* __restrict__ Wf,
    float* __restrict__ num, float* __restrict__ den)
{
    __shared__ unsigned short Kbuf[2][4096];   // 2 x 8KB (64s x 64f, XOR-swz)
    __shared__ unsigned short Vbuf[2][4096];   // 2 x 8KB (tr-subtiled)

    const int tid  = threadIdx.x;
    const int wave = tid >> 6;
    const int lane = tid & 63;
    const int g    = lane >> 4;
    const int lr   = lane & 15;

    // XCD-pinned decode: all 70 (ct,sc) blocks of one (br,b) on one XCD
    const int bid  = blockIdx.x;               // 0..1119
    const int xcd  = bid & 7;
    const int t2   = bid >> 3;                 // 0..139
    const int grp  = xcd + 8 * (t2 / 70);      // 0..15
    const int rest = t2 % 70;
    const int ct   = rest % 35;                // c-tile
    const int sc   = rest / 35;                // S-chunk half
    const int br   = grp >> 2;
    const int b    = grp & 3;
    const int c0   = ct * 256 + wave * 64;
    const int cb0  = sc * 16;                  // first 64-s chunk index

    const float* __restrict__ U =
        (br == 0) ? U3 : (br == 1) ? U5 : (br == 2) ? U7 : U9;

    // ---- Q fragments, phi(g,j) = g*8+j, pre-scaled by log2(e)
    bf16x8 Qf[4][2];
    #pragma unroll
    for (int cs = 0; cs < 4; ++cs) {
        int c = c0 + cs * 16 + lr;
        if (c > C_ - 1) c = C_ - 1;
        const float* Uc = U + (size_t)c * F_;
        #pragma unroll
        for (int kh = 0; kh < 2; ++kh) {
            const float4 lo = *(const float4*)(Uc + kh * 32 + g * 8);
            const float4 hi = *(const float4*)(Uc + kh * 32 + g * 8 + 4);
            bf16x8 q;
            q[0] = bfb(lo.x * LOG2E); q[1] = bfb(lo.y * LOG2E);
            q[2] = bfb(lo.z * LOG2E); q[3] = bfb(lo.w * LOG2E);
            q[4] = bfb(hi.x * LOG2E); q[5] = bfb(hi.y * LOG2E);
            q[6] = bfb(hi.z * LOG2E); q[7] = bfb(hi.w * LOG2E);
            Qf[cs][kh] = q;
        }
    }

    f32x4 acc[4][4];
    #pragma unroll
    for (int cs = 0; cs < 4; ++cs)
        #pragma unroll
        for (int fs = 0; fs < 4; ++fs)
            acc[cs][fs] = (f32x4){0.f, 0.f, 0.f, 0.f};
    float lsum[4] = {0.f, 0.f, 0.f, 0.f};

    const char* hkB = hkG + (size_t)grp * 262144;
    const char* hvB = hvG + (size_t)grp * 262144;
    const unsigned kL0 = (unsigned)(uintptr_t)&Kbuf[0][0];
    const unsigned vL0 = (unsigned)(uintptr_t)&Vbuf[0][0];

#define STAGEKV(chunk, buf) {                                              \
        const size_t go = (size_t)(chunk) * 8192 + wave * 2048 +           \
                          (size_t)(lane << 4);                             \
        const unsigned lo = (unsigned)((buf) * 8192 + wave * 2048);        \
        gl_lds16(hkB + go,        kL0 + lo);                               \
        gl_lds16(hkB + go + 1024, kL0 + lo + 1024);                        \
        gl_lds16(hvB + go,        vL0 + lo);                               \
        gl_lds16(hvB + go + 1024, vL0 + lo + 1024); }

    STAGEKV(cb0, 0)
    __syncthreads();

    const unsigned ksw = ((unsigned)(lr & 7)) << 4;

    for (int t = 0; t < 16; ++t) {
        const int cur = t & 1;
        if (t < 15) STAGEKV(cb0 + t + 1, cur ^ 1)

        // ---- K fragments: one ds_read_b128 each (phi(g,j)=g*8+j)
        const char* Kb = (const char*)Kbuf + cur * 8192;
        bf16x8 Kf[4][2];
        #pragma unroll
        for (int sh = 0; sh < 4; ++sh) {
            const unsigned rowb = (unsigned)((16 * sh + lr) * 128);
            #pragma unroll
            for (int kh = 0; kh < 2; ++kh)
                Kf[sh][kh] = *(const bf16x8*)(
                    Kb + rowb + (((unsigned)(kh * 64 + g * 16)) ^ ksw));
        }

        // ---- QK^T -> exp2 -> P fragments
        bf16x8 Pf[4][2];
        #pragma unroll
        for (int cs = 0; cs < 4; ++cs) {
            f32x4 d0 = (f32x4){0.f,0.f,0.f,0.f}, d1 = d0, d2 = d0, d3 = d0;
            __builtin_amdgcn_s_setprio(1);
            d0 = MFMA16(Kf[0][0], Qf[cs][0], d0);
            d0 = MFMA16(Kf[0][1], Qf[cs][1], d0);
            d1 = MFMA16(Kf[1][0], Qf[cs][0], d1);
            d1 = MFMA16(Kf[1][1], Qf[cs][1], d1);
            d2 = MFMA16(Kf[2][0], Qf[cs][0], d2);
            d2 = MFMA16(Kf[2][1], Qf[cs][1], d2);
            d3 = MFMA16(Kf[3][0], Qf[cs][0], d3);
            d3 = MFMA16(Kf[3][1], Qf[cs][1], d3);
            __builtin_amdgcn_s_setprio(0);
            float p[16];
            #pragma unroll
            for (int r = 0; r < 4; ++r) {
                p[r]      = EXP2F(d0[r]);
                p[4 + r]  = EXP2F(d1[r]);
                p[8 + r]  = EXP2F(d2[r]);
                p[12 + r] = EXP2F(d3[r]);
            }
            float sm = 0.f;
            #pragma unroll
            for (int r = 0; r < 16; ++r) sm += p[r];
            lsum[cs] += sm;
            bf16x8 pf0, pf1;
            #pragma unroll
            for (int r = 0; r < 8; ++r) { pf0[r] = bfb(p[r]); pf1[r] = bfb(p[8 + r]); }
            Pf[cs][0] = pf0;
            Pf[cs][1] = pf1;
        }

        // ---- PV: stream V per fs via hardware transpose-read
        const unsigned vaddr = vL0 + (unsigned)(cur * 8192 + g * 128 + lr * 2);
#define PVBLK(fs, O0, O1, O2, O3)                                          \
        {                                                                  \
            s16x4 a0, a1, b0, b1;                                          \
            TRREAD(a0, O0) TRREAD(a1, O1) TRREAD(b0, O2) TRREAD(b1, O3)    \
            asm volatile("s_waitcnt lgkmcnt(0)" ::: "memory");             \
            __builtin_amdgcn_sched_barrier(0);                             \
            const bf16x8 V0 = __builtin_shufflevector(a0, a1, 0,1,2,3,4,5,6,7); \
            const bf16x8 V1 = __builtin_shufflevector(b0, b1, 0,1,2,3,4,5,6,7); \
            __builtin_amdgcn_s_setprio(1);                                 \
            _Pragma("unroll")                                              \
            for (int cs = 0; cs < 4; ++cs) {                               \
                acc[cs][fs] = MFMA16(Pf[cs][0], V0, acc[cs][fs]);          \
                acc[cs][fs] = MFMA16(Pf[cs][1], V1, acc[cs][fs]);          \
            }                                                              \
            __builtin_amdgcn_s_setprio(0);                                 \
        }
        PVBLK(0,    0,  512, 4096, 4608)
        PVBLK(1, 1024, 1536, 5120, 5632)
        PVBLK(2, 2048, 2560, 6144, 6656)
        PVBLK(3, 3072, 3584, 7168, 7680)

        __syncthreads();
    }

    // ---- denominators: reduce over g-groups, atomicAdd into den
    #pragma unroll
    for (int cs = 0; cs < 4; ++cs) {
        lsum[cs] += __shfl_xor(lsum[cs], 16);
        lsum[cs] += __shfl_xor(lsum[cs], 32);
        if (g == 0) {
            const int cden = c0 + cs * 16 + lr;
            if (cden < C_)
                atomicAdd(&den[(size_t)grp * C_ + cden], lsum[cs]);
        }
    }

    // ---- numerators: unnormalized Wf-dot, 16-lane reduce, atomicAdd
    #pragma unroll
    for (int cs = 0; cs < 4; ++cs) {
        #pragma unroll
        for (int r = 0; r < 4; ++r) {
            const int cc = c0 + cs * 16 + 4 * g + r;
            const int c  = (cc < C_) ? cc : (C_ - 1);
            const float* wrow = Wf + (size_t)c * (4 * F_) + br * F_ + lr;
            float p = 0.f;
            #pragma unroll
            for (int fs = 0; fs < 4; ++fs)
                p += acc[cs][fs][r] * wrow[fs * 16];
            p += __shfl_xor(p, 1);
            p += __shfl_xor(p, 2);
            p += __shfl_xor(p, 4);
            p += __shfl_xor(p, 8);
            if (lr == 0 && cc < C_)
                atomicAdd(&num[(size_t)grp * C_ + cc], p);
        }
    }
}

// ---------------------------------------------------------------------------
// Kernel 3: yh = sum_br num/den + bf; BCE partials
// ---------------------------------------------------------------------------
__global__ __launch_bounds__(256) void bce_kernel(
    const float* __restrict__ num, const float* __restrict__ den,
    const float* __restrict__ bf, const float* __restrict__ y,
    float* __restrict__ out, float* __restrict__ partials)
{
    const int p = blockIdx.x * 256 + threadIdx.x;
    float bce = 0.f;
    if (p < B_ * C_) {
        const int b = p / C_;
        const int c = p - b * C_;
        float yh = bf[c];
        #pragma unroll
        for (int br = 0; br < 4; ++br) {
            const size_t i = (size_t)(br * 4 + b) * C_ + c;
            yh += num[i] / den[i];
        }
        out[p] = yh;
        bce = fmaxf(yh, 0.f) - yh * y[p] + log1pf(expf(-fabsf(yh)));
    }
    __shared__ float red[256];
    red[threadIdx.x] = bce;
    __syncthreads();
    #pragma unroll
    for (int stp = 128; stp > 0; stp >>= 1) {
        if (threadIdx.x < stp) red[threadIdx.x] += red[threadIdx.x + stp];
        __syncthreads();
    }
    if (threadIdx.x == 0) partials[blockIdx.x] = red[0];
}

__global__ __launch_bounds__(256) void loss_kernel(
    const float* __restrict__ partials, int n, float* __restrict__ out_loss)
{
    __shared__ float red[256];
    float v = (threadIdx.x < n) ? partials[threadIdx.x] : 0.f;
    red[threadIdx.x] = v;
    __syncthreads();
    #pragma unroll
    for (int stp = 128; stp > 0; stp >>= 1) {
        if (threadIdx.x < stp) red[threadIdx.x] += red[threadIdx.x + stp];
        __syncthreads();
    }
    if (threadIdx.x == 0) *out_loss = red[0] / (float)(B_ * C_);
}

// ---------------------------------------------------------------------------
extern "C" void kernel_launch(void* const* d_in, const int* in_sizes, int n_in,
                              void* d_out, int out_size, void* d_ws, size_t ws_size,
                              hipStream_t stream)
{
    const int*   x     = (const int*)  d_in[0];
    const float* y     = (const float*)d_in[1];
    const float* embed = (const float*)d_in[2];
    const float* w3    = (const float*)d_in[3];
    const float* b3    = (const float*)d_in[4];
    const float* w5    = (const float*)d_in[5];
    const float* b5    = (const float*)d_in[6];
    const float* w7    = (const float*)d_in[7];
    const float* b7    = (const float*)d_in[8];
    const float* w9    = (const float*)d_in[9];
    const float* b9    = (const float*)d_in[10];
    const float* U3    = (const float*)d_in[11];
    const float* U5    = (const float*)d_in[12];
    const float* U7    = (const float*)d_in[13];
    const float* U9    = (const float*)d_in[14];
    const float* Wf    = (const float*)d_in[15];
    const float* bfv   = (const float*)d_in[16];

    char* wsb = (char*)d_ws;
    float*          num      = (float*)wsb;                     // 142752 f
    float*          den      = (float*)(wsb + 571008);          // 142752 f
    float*          partials = (float*)(wsb + 1142016);         // 140 f
    unsigned short* Wp       = (unsigned short*)(wsb + 1142592);// 294912 bf16
    char*           hkB      = wsb + 1732608;                   // 4 MB
    char*           hvB      = wsb + 1732608 + 4194304;         // 4 MB
    float*          out      = (float*)d_out;

    prep_kernel<<<1152, 256, 0, stream>>>(w3, w5, w7, w9, Wp, num, den);

    conv_mfma_kernel<<<512, 256, 0, stream>>>(
        x, embed, Wp, b3, b5, b7, b9, hkB, hvB);

    attn_mfma_kernel<<<1120, 256, 0, stream>>>(U3, U5, U7, U9, hkB, hvB, Wf,
                                               num, den);

    const int nblk = (B_ * C_ + 255) / 256;   // 140
    bce_kernel<<<nblk, 256, 0, stream>>>(num, den, bfv, y, out, partials);
    loss_kernel<<<1, 256, 0, stream>>>(partials, nblk, out + B_ * C_);
}

// Round 9
// 224.271 us; speedup vs baseline: 20.6660x; 1.0074x over previous
//
#include <hip/hip_runtime.h>
#include <hip/hip_bf16.h>

#define B_ 4
#define S_ 2048
#define E_ 100
#define F_ 64
#define C_ 8922
#define V_ 52000

typedef short bf16x8 __attribute__((ext_vector_type(8)));
typedef short s16x4  __attribute__((ext_vector_type(4)));
typedef float f32x4  __attribute__((ext_vector_type(4)));

#define MFMA16(A, B, C) __builtin_amdgcn_mfma_f32_16x16x32_bf16(A, B, C, 0, 0, 0)
#define LOG2E 1.44269504088896f
#define EXP2F(x) __builtin_amdgcn_exp2f(x)

__device__ inline short bfb(float x) {
    __hip_bfloat16 h = __float2bfloat16(x);
    return *reinterpret_cast<short*>(&h);
}

// ---------------------------------------------------------------------------
// Kernel 0: weight prepack (per-lane MFMA B-fragments, conv k-map
// k = g*4 + (j&3) + ((j>>2)<<4)) + zero num/den/lossAcc/counter.
// ---------------------------------------------------------------------------
__global__ __launch_bounds__(256) void prep_kernel(
    const float* __restrict__ w3, const float* __restrict__ w5,
    const float* __restrict__ w7, const float* __restrict__ w9,
    unsigned short* __restrict__ Wp,
    float* __restrict__ num, float* __restrict__ den,
    float* __restrict__ lossAcc, int* __restrict__ counter)
{
    const int gid = blockIdx.x * 256 + threadIdx.x;   // 0..294911
    if (gid < 4 * B_ * C_) { num[gid] = 0.f; den[gid] = 0.f; }
    if (gid == 0) { *lossAcc = 0.f; *counter = 0; }

    const int j    = gid & 7;
    const int lane = (gid >> 3) & 63;
    const int nt   = (gid >> 9) & 15;
    const int step = gid >> 13;          // 0..35
    const int d    = step >> 2;
    const int ec   = step & 3;
    const int g    = lane >> 4;
    const int lr   = lane & 15;
    const int k    = g * 4 + (j & 3) + ((j >> 2) << 4);
    const int e    = ec * 32 + k;
    const int n    = nt * 16 + lr;
    const int br   = n >> 6;
    const int f    = n & 63;
    const int kb   = 3 + 2 * br;
    const int dp   = d - (3 - br);

    float val = 0.f;
    if (e < E_ && dp >= 0 && dp < kb) {
        const float* w = (br == 0) ? w3 : (br == 1) ? w5 : (br == 2) ? w7 : w9;
        val = w[((size_t)f * E_ + e) * kb + dp];
    }
    Wp[gid] = (unsigned short)bfb(val);
}

// ---------------------------------------------------------------------------
// h bf16 global layouts (byte-identical to R3..R7 validated layouts):
//  hk per (br,b): s*128 + (f*2 ^ ((s&7)<<4))
//  hv per (br,b): (s>>5)*4096 + (f>>4)*1024 + ((s>>4)&1)*512
//                 + ((s>>2)&3)*128 + (s&3)*32 + (f&15)*2
// ---------------------------------------------------------------------------

// ---------------------------------------------------------------------------
// Kernel 1: conv as MFMA GEMM, 16-s tiles, register-DOUBLE-BUFFERED B-frags
// (the R7 version left Bf loads serialized: 36 steps x ~250cy L2 latency).
// ---------------------------------------------------------------------------
__global__ __launch_bounds__(256, 2) void conv_mfma_kernel(
    const int* __restrict__ x, const float* __restrict__ embed,
    const unsigned short* __restrict__ Wp,
    const float* __restrict__ b3, const float* __restrict__ b5,
    const float* __restrict__ b7, const float* __restrict__ b9,
    char* __restrict__ hkB, char* __restrict__ hvB)
{
    __shared__ unsigned short xeT[24 * 128];   // 6 KB swizzled bf16 tile
    __shared__ float ep[4][16][68];            // 17 KB epilogue bounce

    const int blk  = blockIdx.x;
    const int b    = blk >> 7;
    const int st   = blk & 127;
    const int s0   = st * 16;
    const int tid  = threadIdx.x;
    const int wave = tid >> 6;
    const int lane = tid & 63;
    const int g    = lane >> 4;
    const int lr   = lane & 15;

    // ---- stage xe: 24 rows x 128 e (bf16, row-XOR swizzled)
    for (int task = tid; task < 384; task += 256) {
        const int row = task >> 4;
        const int o   = task & 15;
        const int s   = s0 - 4 + row;
        float v[8];
        #pragma unroll
        for (int i = 0; i < 8; ++i) v[i] = 0.f;
        if (s >= 0 && s < S_ && o < 13) {
            const int tok = x[b * S_ + s];
            const float* er = embed + (size_t)tok * E_ + o * 8;
            if (o < 12) {
                #pragma unroll
                for (int i = 0; i < 8; ++i) v[i] = er[i];
            } else {
                v[0] = er[0]; v[1] = er[1]; v[2] = er[2]; v[3] = er[3];
            }
        }
        unsigned short u[8];
        #pragma unroll
        for (int i = 0; i < 8; ++i) u[i] = (unsigned short)bfb(v[i]);
        const unsigned xr = ((unsigned)(row & 15)) << 3;
        char* base = (char*)xeT + row * 256;
        *(uint2*)(base + (((unsigned)(o * 16)) ^ xr))     = *(const uint2*)&u[0];
        *(uint2*)(base + (((unsigned)(o * 16 + 8)) ^ xr)) = *(const uint2*)&u[4];
    }
    __syncthreads();

    f32x4 acc[4];
    #pragma unroll
    for (int ns = 0; ns < 4; ++ns) acc[ns] = (f32x4){0.f, 0.f, 0.f, 0.f};

    const char* xb = (const char*)xeT;
    const unsigned short* wpb = Wp + ((size_t)wave * 4) * 512 + lane * 8;

#define LOADB(v0, v1, v2, v3, stepv) {                                     \
        const unsigned short* wp = wpb + (size_t)(stepv) * 8192;           \
        v0 = *(const bf16x8*)(wp);        v1 = *(const bf16x8*)(wp + 512); \
        v2 = *(const bf16x8*)(wp + 1024); v3 = *(const bf16x8*)(wp + 1536); }

#define AFLOAD(Afv, stepv) {                                               \
        const int row = lr + ((stepv) >> 2);                               \
        const unsigned xr = ((unsigned)(row & 15)) << 3;                   \
        const unsigned rb = (unsigned)row * 256;                           \
        const unsigned e0 = (unsigned)((((stepv) & 3)) * 64 + g * 8);      \
        const s16x4 lo = *(const s16x4*)(xb + rb + (e0 ^ xr));             \
        const s16x4 hi = *(const s16x4*)(xb + rb + ((e0 + 32) ^ xr));      \
        Afv = __builtin_shufflevector(lo, hi, 0, 1, 2, 3, 4, 5, 6, 7); }

    bf16x8 A0, A1;
    bf16x8 B00, B01, B02, B03, B10, B11, B12, B13;
    LOADB(B00, B01, B02, B03, 0)
    AFLOAD(A0, 0)

    #pragma unroll
    for (int sp = 0; sp < 36; sp += 2) {
        LOADB(B10, B11, B12, B13, sp + 1)
        AFLOAD(A1, sp + 1)
        acc[0] = MFMA16(A0, B00, acc[0]);
        acc[1] = MFMA16(A0, B01, acc[1]);
        acc[2] = MFMA16(A0, B02, acc[2]);
        acc[3] = MFMA16(A0, B03, acc[3]);
        if (sp < 34) {
            LOADB(B00, B01, B02, B03, sp + 2)
            AFLOAD(A0, sp + 2)
        }
        acc[0] = MFMA16(A1, B10, acc[0]);
        acc[1] = MFMA16(A1, B11, acc[1]);
        acc[2] = MFMA16(A1, B12, acc[2]);
        acc[3] = MFMA16(A1, B13, acc[3]);
    }

    // ---- epilogue: bias+tanh -> LDS -> vectorized 16B stores to hk & hv
    const float* bias = (wave == 0) ? b3 : (wave == 1) ? b5 : (wave == 2) ? b7 : b9;
    float bia[4];
    #pragma unroll
    for (int ns = 0; ns < 4; ++ns) bia[ns] = bias[ns * 16 + lr];

    #pragma unroll
    for (int ns = 0; ns < 4; ++ns)
        #pragma unroll
        for (int r = 0; r < 4; ++r)
            ep[wave][4 * g + r][ns * 16 + lr] = tanhf(acc[ns][r] + bia[ns]);
    __syncthreads();

    const size_t hbase = (size_t)(wave * 4 + b) * 262144;   // per (br,b) 256 KB
    #pragma unroll
    for (int it = 0; it < 2; ++it) {
        const int task = it * 64 + lane;
        const int sl = task >> 3;        // 0..15
        const int o  = task & 7;         // f-octet
        const int s  = s0 + sl;
        float v[8];
        *(float4*)&v[0] = *(const float4*)&ep[wave][sl][o * 8];
        *(float4*)&v[4] = *(const float4*)&ep[wave][sl][o * 8 + 4];
        unsigned short u[8];
        #pragma unroll
        for (int i = 0; i < 8; ++i) u[i] = (unsigned short)bfb(v[i]);
        uint4 pk;
        pk.x = (unsigned)u[0] | ((unsigned)u[1] << 16);
        pk.y = (unsigned)u[2] | ((unsigned)u[3] << 16);
        pk.z = (unsigned)u[4] | ((unsigned)u[5] << 16);
        pk.w = (unsigned)u[6] | ((unsigned)u[7] << 16);
        char* hka = hkB + hbase + (size_t)s * 128 +
                    (((unsigned)(o * 16)) ^ (((unsigned)(s & 7)) << 4));
        *(uint4*)hka = pk;
        char* hva = hvB + hbase + (size_t)(s >> 5) * 4096 + (o >> 1) * 1024 +
                    ((s >> 4) & 1) * 512 + ((s >> 2) & 3) * 128 +
                    (s & 3) * 32 + (o & 1) * 16;
        *(uint4*)hva = pk;
    }
}

// ---------------------------------------------------------------------------
// Kernel 2: bf16 MFMA flash attention, KVBLK=64, S-split x2, XCD-pinned grid,
// PV software-pipelined with counted lgkmcnt(4), fused Wf epilogue.
// ---------------------------------------------------------------------------
#define TRREAD(dst, off) \
    asm volatile("ds_read_b64_tr_b16 %0, %1 offset:" #off \
                 : "=v"(dst) : "v"(vaddr));

typedef const __attribute__((address_space(1))) unsigned int* as1_u32p;
typedef __attribute__((address_space(3))) unsigned int* as3_u32p;

__device__ inline void gl_lds16(const void* g, unsigned lds_off) {
    __builtin_amdgcn_global_load_lds((as1_u32p)(uintptr_t)g,
                                     (as3_u32p)(uintptr_t)lds_off, 16, 0, 0);
}

__global__ __launch_bounds__(256, 2) void attn_mfma_kernel(
    const float* __restrict__ U3, const float* __restrict__ U5,
    const float* __restrict__ U7, const float* __restrict__ U9,
    const char* __restrict__ hkG, const char* __restrict__ hvG,
    const float* __restrict__ Wf,
    float* __restrict__ num, float* __restrict__ den)
{
    __shared__ unsigned short Kbuf[2][4096];   // 2 x 8KB (64s x 64f, XOR-swz)
    __shared__ unsigned short Vbuf[2][4096];   // 2 x 8KB (tr-subtiled)

    const int tid  = threadIdx.x;
    const int wave = tid >> 6;
    const int lane = tid & 63;
    const int g    = lane >> 4;
    const int lr   = lane & 15;

    // XCD-pinned decode: all 70 (ct,sc) blocks of one (br,b) on one XCD
    const int bid  = blockIdx.x;               // 0..1119
    const int xcd  = bid & 7;
    const int t2   = bid >> 3;                 // 0..139
    const int grp  = xcd + 8 * (t2 / 70);      // 0..15
    const int rest = t2 % 70;
    const int ct   = rest % 35;                // c-tile
    const int sc   = rest / 35;                // S-chunk half
    const int br   = grp >> 2;
    const int b    = grp & 3;
    const int c0   = ct * 256 + wave * 64;
    const int cb0  = sc * 16;                  // first 64-s chunk index

    const float* __restrict__ U =
        (br == 0) ? U3 : (br == 1) ? U5 : (br == 2) ? U7 : U9;

    // ---- Q fragments, phi(g,j) = g*8+j, pre-scaled by log2(e)
    bf16x8 Qf[4][2];
    #pragma unroll
    for (int cs = 0; cs < 4; ++cs) {
        int c = c0 + cs * 16 + lr;
        if (c > C_ - 1) c = C_ - 1;
        const float* Uc = U + (size_t)c * F_;
        #pragma unroll
        for (int kh = 0; kh < 2; ++kh) {
            const float4 lo = *(const float4*)(Uc + kh * 32 + g * 8);
            const float4 hi = *(const float4*)(Uc + kh * 32 + g * 8 + 4);
            bf16x8 q;
            q[0] = bfb(lo.x * LOG2E); q[1] = bfb(lo.y * LOG2E);
            q[2] = bfb(lo.z * LOG2E); q[3] = bfb(lo.w * LOG2E);
            q[4] = bfb(hi.x * LOG2E); q[5] = bfb(hi.y * LOG2E);
            q[6] = bfb(hi.z * LOG2E); q[7] = bfb(hi.w * LOG2E);
            Qf[cs][kh] = q;
        }
    }

    f32x4 acc[4][4];
    #pragma unroll
    for (int cs = 0; cs < 4; ++cs)
        #pragma unroll
        for (int fs = 0; fs < 4; ++fs)
            acc[cs][fs] = (f32x4){0.f, 0.f, 0.f, 0.f};
    float lsum[4] = {0.f, 0.f, 0.f, 0.f};

    const char* hkB = hkG + (size_t)grp * 262144;
    const char* hvB = hvG + (size_t)grp * 262144;
    const unsigned kL0 = (unsigned)(uintptr_t)&Kbuf[0][0];
    const unsigned vL0 = (unsigned)(uintptr_t)&Vbuf[0][0];

#define STAGEKV(chunk, buf) {                                              \
        const size_t go = (size_t)(chunk) * 8192 + wave * 2048 +           \
                          (size_t)(lane << 4);                             \
        const unsigned lo = (unsigned)((buf) * 8192 + wave * 2048);        \
        gl_lds16(hkB + go,        kL0 + lo);                               \
        gl_lds16(hkB + go + 1024, kL0 + lo + 1024);                        \
        gl_lds16(hvB + go,        vL0 + lo);                               \
        gl_lds16(hvB + go + 1024, vL0 + lo + 1024); }

    STAGEKV(cb0, 0)
    __syncthreads();

    const unsigned ksw = ((unsigned)(lr & 7)) << 4;

    for (int t = 0; t < 16; ++t) {
        const int cur = t & 1;
        if (t < 15) STAGEKV(cb0 + t + 1, cur ^ 1)

        // ---- K fragments: one ds_read_b128 each (phi(g,j)=g*8+j)
        const char* Kb = (const char*)Kbuf + cur * 8192;
        bf16x8 Kf[4][2];
        #pragma unroll
        for (int sh = 0; sh < 4; ++sh) {
            const unsigned rowb = (unsigned)((16 * sh + lr) * 128);
            #pragma unroll
            for (int kh = 0; kh < 2; ++kh)
                Kf[sh][kh] = *(const bf16x8*)(
                    Kb + rowb + (((unsigned)(kh * 64 + g * 16)) ^ ksw));
        }

        // ---- QK^T -> exp2 -> P fragments
        bf16x8 Pf[4][2];
        #pragma unroll
        for (int cs = 0; cs < 4; ++cs) {
            f32x4 d0 = (f32x4){0.f,0.f,0.f,0.f}, d1 = d0, d2 = d0, d3 = d0;
            __builtin_amdgcn_s_setprio(1);
            d0 = MFMA16(Kf[0][0], Qf[cs][0], d0);
            d0 = MFMA16(Kf[0][1], Qf[cs][1], d0);
            d1 = MFMA16(Kf[1][0], Qf[cs][0], d1);
            d1 = MFMA16(Kf[1][1], Qf[cs][1], d1);
            d2 = MFMA16(Kf[2][0], Qf[cs][0], d2);
            d2 = MFMA16(Kf[2][1], Qf[cs][1], d2);
            d3 = MFMA16(Kf[3][0], Qf[cs][0], d3);
            d3 = MFMA16(Kf[3][1], Qf[cs][1], d3);
            __builtin_amdgcn_s_setprio(0);
            float p[16];
            #pragma unroll
            for (int r = 0; r < 4; ++r) {
                p[r]      = EXP2F(d0[r]);
                p[4 + r]  = EXP2F(d1[r]);
                p[8 + r]  = EXP2F(d2[r]);
                p[12 + r] = EXP2F(d3[r]);
            }
            float sm = 0.f;
            #pragma unroll
            for (int r = 0; r < 16; ++r) sm += p[r];
            lsum[cs] += sm;
            bf16x8 pf0, pf1;
            #pragma unroll
            for (int r = 0; r < 8; ++r) { pf0[r] = bfb(p[r]); pf1[r] = bfb(p[8 + r]); }
            Pf[cs][0] = pf0;
            Pf[cs][1] = pf1;
        }

        // ---- PV: software-pipelined tr-reads (counted lgkmcnt), 2 reg groups
        const unsigned vaddr = vL0 + (unsigned)(cur * 8192 + g * 128 + lr * 2);
        {
            s16x4 pa, pb, pc, pd, qa, qb, qc, qd;
            __builtin_amdgcn_sched_barrier(0);   // pin: only TRREADs below
            TRREAD(pa, 0)    TRREAD(pb, 512)  TRREAD(pc, 4096) TRREAD(pd, 4608)
            TRREAD(qa, 1024) TRREAD(qb, 1536) TRREAD(qc, 5120) TRREAD(qd, 5632)
            asm volatile("s_waitcnt lgkmcnt(4)" ::: "memory");
            __builtin_amdgcn_sched_barrier(0);
            {
                const bf16x8 V0 = __builtin_shufflevector(pa, pb, 0,1,2,3,4,5,6,7);
                const bf16x8 V1 = __builtin_shufflevector(pc, pd, 0,1,2,3,4,5,6,7);
                __builtin_amdgcn_s_setprio(1);
                #pragma unroll
                for (int cs = 0; cs < 4; ++cs) {
                    acc[cs][0] = MFMA16(Pf[cs][0], V0, acc[cs][0]);
                    acc[cs][0] = MFMA16(Pf[cs][1], V1, acc[cs][0]);
                }
                __builtin_amdgcn_s_setprio(0);
            }
            TRREAD(pa, 2048) TRREAD(pb, 2560) TRREAD(pc, 6144) TRREAD(pd, 6656)
            asm volatile("s_waitcnt lgkmcnt(4)" ::: "memory");
            __builtin_amdgcn_sched_barrier(0);
            {
                const bf16x8 V0 = __builtin_shufflevector(qa, qb, 0,1,2,3,4,5,6,7);
                const bf16x8 V1 = __builtin_shufflevector(qc, qd, 0,1,2,3,4,5,6,7);
                __builtin_amdgcn_s_setprio(1);
                #pragma unroll
                for (int cs = 0; cs < 4; ++cs) {
                    acc[cs][1] = MFMA16(Pf[cs][0], V0, acc[cs][1]);
                    acc[cs][1] = MFMA16(Pf[cs][1], V1, acc[cs][1]);
                }
                __builtin_amdgcn_s_setprio(0);
            }
            TRREAD(qa, 3072) TRREAD(qb, 3584) TRREAD(qc, 7168) TRREAD(qd, 7680)
            asm volatile("s_waitcnt lgkmcnt(4)" ::: "memory");
            __builtin_amdgcn_sched_barrier(0);
            {
                const bf16x8 V0 = __builtin_shufflevector(pa, pb, 0,1,2,3,4,5,6,7);
                const bf16x8 V1 = __builtin_shufflevector(pc, pd, 0,1,2,3,4,5,6,7);
                __builtin_amdgcn_s_setprio(1);
                #pragma unroll
                for (int cs = 0; cs < 4; ++cs) {
                    acc[cs][2] = MFMA16(Pf[cs][0], V0, acc[cs][2]);
                    acc[cs][2] = MFMA16(Pf[cs][1], V1, acc[cs][2]);
                }
                __builtin_amdgcn_s_setprio(0);
            }
            asm volatile("s_waitcnt lgkmcnt(0)" ::: "memory");
            __builtin_amdgcn_sched_barrier(0);
            {
                const bf16x8 V0 = __builtin_shufflevector(qa, qb, 0,1,2,3,4,5,6,7);
                const bf16x8 V1 = __builtin_shufflevector(qc, qd, 0,1,2,3,4,5,6,7);
                __builtin_amdgcn_s_setprio(1);
                #pragma unroll
                for (int cs = 0; cs < 4; ++cs) {
                    acc[cs][3] = MFMA16(Pf[cs][0], V0, acc[cs][3]);
                    acc[cs][3] = MFMA16(Pf[cs][1], V1, acc[cs][3]);
                }
                __builtin_amdgcn_s_setprio(0);
            }
        }

        __syncthreads();
    }

    // ---- denominators: reduce over g-groups, atomicAdd into den
    #pragma unroll
    for (int cs = 0; cs < 4; ++cs) {
        lsum[cs] += __shfl_xor(lsum[cs], 16);
        lsum[cs] += __shfl_xor(lsum[cs], 32);
        if (g == 0) {
            const int cden = c0 + cs * 16 + lr;
            if (cden < C_)
                atomicAdd(&den[(size_t)grp * C_ + cden], lsum[cs]);
        }
    }

    // ---- numerators: unnormalized Wf-dot, 16-lane reduce, atomicAdd
    #pragma unroll
    for (int cs = 0; cs < 4; ++cs) {
        #pragma unroll
        for (int r = 0; r < 4; ++r) {
            const int cc = c0 + cs * 16 + 4 * g + r;
            const int c  = (cc < C_) ? cc : (C_ - 1);
            const float* wrow = Wf + (size_t)c * (4 * F_) + br * F_ + lr;
            float p = 0.f;
            #pragma unroll
            for (int fs = 0; fs < 4; ++fs)
                p += acc[cs][fs][r] * wrow[fs * 16];
            p += __shfl_xor(p, 1);
            p += __shfl_xor(p, 2);
            p += __shfl_xor(p, 4);
            p += __shfl_xor(p, 8);
            if (lr == 0 && cc < C_)
                atomicAdd(&num[(size_t)grp * C_ + cc], p);
        }
    }
}

// ---------------------------------------------------------------------------
// Kernel 3: yh = sum_br num/den + bf; BCE; fused final loss via last-block
// ---------------------------------------------------------------------------
__global__ __launch_bounds__(256) void bce_kernel(
    const float* __restrict__ num, const float* __restrict__ den,
    const float* __restrict__ bf, const float* __restrict__ y,
    float* __restrict__ out, float* __restrict__ lossAcc,
    int* __restrict__ counter)
{
    const int p = blockIdx.x * 256 + threadIdx.x;
    float bce = 0.f;
    if (p < B_ * C_) {
        const int b = p / C_;
        const int c = p - b * C_;
        float yh = bf[c];
        #pragma unroll
        for (int br = 0; br < 4; ++br) {
            const size_t i = (size_t)(br * 4 + b) * C_ + c;
            yh += num[i] / den[i];
        }
        out[p] = yh;
        bce = fmaxf(yh, 0.f) - yh * y[p] + log1pf(expf(-fabsf(yh)));
    }
    __shared__ float red[256];
    red[threadIdx.x] = bce;
    __syncthreads();
    #pragma unroll
    for (int stp = 128; stp > 0; stp >>= 1) {
        if (threadIdx.x < stp) red[threadIdx.x] += red[threadIdx.x + stp];
        __syncthreads();
    }
    if (threadIdx.x == 0) {
        atomicAdd(lossAcc, red[0]);
        __threadfence();
        const int done = atomicAdd(counter, 1);
        if (done == (int)gridDim.x - 1) {
            __threadfence();
            const float total = atomicAdd(lossAcc, 0.f);   // read via L2
            out[B_ * C_] = total / (float)(B_ * C_);
        }
    }
}

// ---------------------------------------------------------------------------
extern "C" void kernel_launch(void* const* d_in, const int* in_sizes, int n_in,
                              void* d_out, int out_size, void* d_ws, size_t ws_size,
                              hipStream_t stream)
{
    const int*   x     = (const int*)  d_in[0];
    const float* y     = (const float*)d_in[1];
    const float* embed = (const float*)d_in[2];
    const float* w3    = (const float*)d_in[3];
    const float* b3    = (const float*)d_in[4];
    const float* w5    = (const float*)d_in[5];
    const float* b5    = (const float*)d_in[6];
    const float* w7    = (const float*)d_in[7];
    const float* b7    = (const float*)d_in[8];
    const float* w9    = (const float*)d_in[9];
    const float* b9    = (const float*)d_in[10];
    const float* U3    = (const float*)d_in[11];
    const float* U5    = (const float*)d_in[12];
    const float* U7    = (const float*)d_in[13];
    const float* U9    = (const float*)d_in[14];
    const float* Wf    = (const float*)d_in[15];
    const float* bfv   = (const float*)d_in[16];

    char* wsb = (char*)d_ws;
    float*          num      = (float*)wsb;                     // 142752 f
    float*          den      = (float*)(wsb + 571008);          // 142752 f
    float*          lossAcc  = (float*)(wsb + 1142016);
    int*            counter  = (int*)  (wsb + 1142020);
    unsigned short* Wp       = (unsigned short*)(wsb + 1142592);// 294912 bf16
    char*           hkB      = wsb + 1732608;                   // 4 MB
    char*           hvB      = wsb + 1732608 + 4194304;         // 4 MB
    float*          out      = (float*)d_out;

    prep_kernel<<<1152, 256, 0, stream>>>(w3, w5, w7, w9, Wp, num, den,
                                          lossAcc, counter);

    conv_mfma_kernel<<<512, 256, 0, stream>>>(
        x, embed, Wp, b3, b5, b7, b9, hkB, hvB);

    attn_mfma_kernel<<<1120, 256, 0, stream>>>(U3, U5, U7, U9, hkB, hvB, Wf,
                                               num, den);

    const int nblk = (B_ * C_ + 255) / 256;   // 140
    bce_kernel<<<nblk, 256, 0, stream>>>(num, den, bfv, y, out,
                                         lossAcc, counter);
}